// Round 1
// baseline (4083.902 us; speedup 1.0000x reference)
//
#include <hip/hip_runtime.h>
#include <math.h>

#define N_NODES 100000
#define N_HEDGES 200000
#define N_INC 1000000
#define N_GRAPHS 256
#define HD 64
#define HE 35
#define CAT 99
#define HOUT 128
#define EPSB 1e-5f

__device__ __forceinline__ float sp_f(float x) {
  // jax.nn.softplus = max(x,0) + log1p(exp(-|x|))
  return fmaxf(x, 0.f) + log1pf(expf(-fabsf(x)));
}
__device__ __forceinline__ float sig_f(float x) {
  return 1.f / (1.f + expf(-x));
}

// -------------------- counts --------------------
__global__ __launch_bounds__(256) void k_count(const int* __restrict__ nidx,
                                               const int* __restrict__ hidx,
                                               float* __restrict__ cnt_h,
                                               float* __restrict__ cnt_n) {
  int e = blockIdx.x * 256 + threadIdx.x;
  if (e >= N_INC) return;
  atomicAdd(&cnt_h[hidx[e]], 1.f);
  atomicAdd(&cnt_n[nidx[e]], 1.f);
}

__global__ __launch_bounds__(256) void k_invert(float* __restrict__ v, int n) {
  int i = blockIdx.x * 256 + threadIdx.x;
  if (i < n) v[i] = 1.f / fmaxf(v[i], 1.f);
}

// -------------------- embed: x[N,92] @ w[92,64] + b --------------------
__global__ __launch_bounds__(256) void k_embed(const float* __restrict__ x,
                                               const float* __restrict__ w,
                                               const float* __restrict__ b,
                                               float* __restrict__ out) {
  __shared__ float ws[92 * 64];
  __shared__ float rs[16][93];
  int tid = threadIdx.x;
  for (int i = tid; i < 92 * 64; i += 256) ws[i] = w[i];
  int r0 = blockIdx.x * 16;
  for (int i = tid; i < 16 * 92; i += 256) {
    int r = i / 92, k = i - r * 92;
    rs[r][k] = x[(r0 + r) * 92 + k];
  }
  __syncthreads();
  int h = tid & 63;
  float bias = b[h];
  for (int rr = tid >> 6; rr < 16; rr += 4) {
    float acc = bias;
    for (int k = 0; k < 92; ++k) acc += rs[rr][k] * ws[k * 64 + h];
    out[(r0 + rr) * 64 + h] = acc;
  }
}

// -------------------- scatter x rows into hedge accumulator --------------------
__global__ __launch_bounds__(256) void k_scatter_hx(const float* __restrict__ x,
                                                    const int* __restrict__ nidx,
                                                    const int* __restrict__ hidx,
                                                    float* __restrict__ hx) {
  int t = blockIdx.x * 256 + threadIdx.x;  // < 64e6
  int e = t >> 6;
  int h = t & 63;
  int nd = nidx[e];
  int hg = hidx[e];
  atomicAdd(&hx[hg * 64 + h], x[nd * 64 + h]);
}

// -------------------- hedge matvec + BN (two passes) --------------------
#define HB 32
template <int PASS>
__global__ __launch_bounds__(256) void k_hedge(
    const float* __restrict__ hx, const float* __restrict__ invh,
    const float* __restrict__ ha_in,
    const float* __restrict__ w_f, const float* __restrict__ b_f,
    const float* __restrict__ w_c, const float* __restrict__ b_c,
    const float* __restrict__ gf, const float* __restrict__ bf_,
    const float* __restrict__ gc, const float* __restrict__ bc_,
    float* __restrict__ stats, float* __restrict__ ha_out) {
  __shared__ float wf[CAT * HE];
  __shared__ float wc[CAT * HE];
  __shared__ float msg[HB][CAT + 1];
  __shared__ float ps[140];
  int tid = threadIdx.x;
  for (int i = tid; i < CAT * HE; i += 256) {
    wf[i] = w_f[i];
    wc[i] = w_c[i];
  }
  if (PASS == 1)
    for (int i = tid; i < 140; i += 256) ps[i] = 0.f;
  int j0 = blockIdx.x * HB;
  for (int i = tid; i < HB * CAT; i += 256) {
    int r = i / CAT, k = i - r * CAT;
    int j = j0 + r;
    msg[r][k] = (k < HD) ? hx[j * HD + k] * invh[j] : ha_in[j * HE + (k - HD)];
  }
  __syncthreads();
  for (int p = tid; p < HB * HE; p += 256) {
    int r = p / HE, c = p - r * HE;
    float zf = b_f[c], zc = b_c[c];
    const float* m = msg[r];
    for (int k = 0; k < CAT; ++k) {
      float v = m[k];
      zf += v * wf[k * HE + c];
      zc += v * wc[k * HE + c];
    }
    if (PASS == 1) {
      atomicAdd(&ps[c], zf);
      atomicAdd(&ps[35 + c], zf * zf);
      atomicAdd(&ps[70 + c], zc);
      atomicAdd(&ps[105 + c], zc * zc);
    } else {
      float mf = stats[c] * (1.f / N_HEDGES);
      float vf = stats[35 + c] * (1.f / N_HEDGES) - mf * mf;
      float mc = stats[70 + c] * (1.f / N_HEDGES);
      float vc = stats[105 + c] * (1.f / N_HEDGES) - mc * mc;
      float nf = (zf - mf) * rsqrtf(vf + EPSB) * gf[c] + bf_[c];
      float nc = (zc - mc) * rsqrtf(vc + EPSB) * gc[c] + bc_[c];
      ha_out[(j0 + r) * HE + c] = sig_f(nf) * sp_f(nc);
    }
  }
  if (PASS == 1) {
    __syncthreads();
    if (tid < 140) atomicAdd(&stats[tid], ps[tid]);
  }
}

// -------------------- per-node projection: U = x @ W[0:64,:] --------------------
__global__ __launch_bounds__(256) void k_uv_node(const float* __restrict__ x,
                                                 const float* __restrict__ f2w,
                                                 const float* __restrict__ c2w,
                                                 float* __restrict__ Uf,
                                                 float* __restrict__ Uc) {
  __shared__ float wf[64 * 64];
  __shared__ float wc[64 * 64];
  __shared__ float rs[16][65];
  int tid = threadIdx.x;
  for (int i = tid; i < 64 * 64; i += 256) {
    wf[i] = f2w[i];
    wc[i] = c2w[i];
  }
  int r0 = blockIdx.x * 16;
  for (int i = tid; i < 16 * 64; i += 256) {
    int r = i >> 6, k = i & 63;
    rs[r][k] = x[(r0 + r) * 64 + k];
  }
  __syncthreads();
  int h = tid & 63;
  for (int rr = tid >> 6; rr < 16; rr += 4) {
    float af = 0.f, ac = 0.f;
    for (int k = 0; k < 64; ++k) {
      float v = rs[rr][k];
      af += v * wf[k * 64 + h];
      ac += v * wc[k * 64 + h];
    }
    int row = r0 + rr;
    Uf[row * 64 + h] = af;
    Uc[row * 64 + h] = ac;
  }
}

// ---------------- per-hedge projection: V = ha @ W[64:99,:] + bias ----------------
__global__ __launch_bounds__(256) void k_uv_hedge(const float* __restrict__ ha,
                                                  const float* __restrict__ f2wb,
                                                  const float* __restrict__ c2wb,
                                                  const float* __restrict__ f2b,
                                                  const float* __restrict__ c2b,
                                                  float* __restrict__ Vf,
                                                  float* __restrict__ Vc) {
  __shared__ float wf[35 * 64];
  __shared__ float wc[35 * 64];
  __shared__ float rs[16][36];
  int tid = threadIdx.x;
  for (int i = tid; i < 35 * 64; i += 256) {
    wf[i] = f2wb[i];
    wc[i] = c2wb[i];
  }
  int r0 = blockIdx.x * 16;
  for (int i = tid; i < 16 * 35; i += 256) {
    int r = i / 35, k = i - r * 35;
    rs[r][k] = ha[(r0 + r) * 35 + k];
  }
  __syncthreads();
  int h = tid & 63;
  float bf = f2b[h], bc = c2b[h];
  for (int rr = tid >> 6; rr < 16; rr += 4) {
    float af = bf, ac = bc;
    for (int k = 0; k < 35; ++k) {
      float v = rs[rr][k];
      af += v * wf[k * 64 + h];
      ac += v * wc[k * 64 + h];
    }
    int row = r0 + rr;
    Vf[row * 64 + h] = af;
    Vc[row * 64 + h] = ac;
  }
}

// ------------- per-incidence: o[node] += sig(Uf+Vf) * sp(Uc+Vc) -------------
__global__ __launch_bounds__(256) void k_inc2(const int* __restrict__ nidx,
                                              const int* __restrict__ hidx,
                                              const float* __restrict__ Uf,
                                              const float* __restrict__ Uc,
                                              const float* __restrict__ Vf,
                                              const float* __restrict__ Vc,
                                              float* __restrict__ o) {
  int t = blockIdx.x * 256 + threadIdx.x;  // < 64e6
  int e = t >> 6;
  int h = t & 63;
  int nd = nidx[e];
  int hg = hidx[e];
  float af = Uf[nd * 64 + h] + Vf[hg * 64 + h];
  float ac = Uc[nd * 64 + h] + Vc[hg * 64 + h];
  atomicAdd(&o[nd * 64 + h], sig_f(af) * sp_f(ac));
}

// -------------------- BN stats over node features --------------------
__global__ __launch_bounds__(256) void k_ostats(const float* __restrict__ o,
                                                const float* __restrict__ invn,
                                                float* __restrict__ stats) {
  int h = threadIdx.x & 63;
  int rs = threadIdx.x >> 6;
  float s = 0.f, sq = 0.f;
  for (int r = blockIdx.x * 4 + rs; r < N_NODES; r += gridDim.x * 4) {
    float v = o[r * 64 + h] * invn[r];
    s += v;
    sq += v * v;
  }
  __shared__ float ls[4][2][64];
  ls[rs][0][h] = s;
  ls[rs][1][h] = sq;
  __syncthreads();
  if (threadIdx.x < 64) {
    float ts = ls[0][0][h] + ls[1][0][h] + ls[2][0][h] + ls[3][0][h];
    float tq = ls[0][1][h] + ls[1][1][h] + ls[2][1][h] + ls[3][1][h];
    atomicAdd(&stats[h], ts);
    atomicAdd(&stats[64 + h], tq);
  }
}

// -------------------- x = softplus(BN(o_mean) + x) --------------------
__global__ __launch_bounds__(256) void k_update(float* __restrict__ x,
                                                const float* __restrict__ o,
                                                const float* __restrict__ invn,
                                                const float* __restrict__ stats,
                                                const float* __restrict__ g,
                                                const float* __restrict__ b) {
  int t = blockIdx.x * 256 + threadIdx.x;  // N*64
  int h = t & 63;
  int r = t >> 6;
  float mean = stats[h] * (1.f / N_NODES);
  float var = stats[64 + h] * (1.f / N_NODES) - mean * mean;
  float is = rsqrtf(var + EPSB);
  float v = (o[t] * invn[r] - mean) * is * g[h] + b[h];
  x[t] = sp_f(v + x[t]);
}

// -------------------- graph pooling --------------------
__global__ __launch_bounds__(256) void k_pool(const float* __restrict__ x,
                                              const int* __restrict__ batch,
                                              float* __restrict__ pooled,
                                              float* __restrict__ gcnt) {
  int t = blockIdx.x * 256 + threadIdx.x;  // N*64
  int r = t >> 6;
  int h = t & 63;
  int g = batch[r];
  atomicAdd(&pooled[g * 64 + h], x[t]);
  if (h == 0) atomicAdd(&gcnt[g], 1.f);
}

// -------------------- final dense layers --------------------
__global__ __launch_bounds__(128) void k_final(const float* __restrict__ pooled,
                                               const float* __restrict__ gcnt,
                                               const float* __restrict__ l2w,
                                               const float* __restrict__ l2b,
                                               const float* __restrict__ ow,
                                               const float* __restrict__ ob,
                                               float* __restrict__ out) {
  int g = blockIdx.x;
  int t = threadIdx.x;
  __shared__ float row[64];
  __shared__ float hh[128];
  if (t < 64) row[t] = pooled[g * 64 + t] / fmaxf(gcnt[g], 1.f);
  __syncthreads();
  float acc = l2b[t];
  for (int k = 0; k < 64; ++k) acc += row[k] * l2w[k * 128 + t];
  hh[t] = sp_f(acc) * ow[t];
  __syncthreads();
  for (int s = 64; s > 0; s >>= 1) {
    if (t < s) hh[t] += hh[t + s];
    __syncthreads();
  }
  if (t == 0) out[g] = hh[0] + ob[0];
}

extern "C" void kernel_launch(void* const* d_in, const int* in_sizes, int n_in,
                              void* d_out, int out_size, void* d_ws, size_t ws_size,
                              hipStream_t stream) {
  const float* x_in = (const float*)d_in[0];
  const int* node_idx = (const int*)d_in[1];
  const int* hedge_idx = (const int*)d_in[2];
  const float* hedge_attr = (const float*)d_in[3];
  const int* batch = (const int*)d_in[4];
  const float* embed_w = (const float*)d_in[5];
  const float* embed_b = (const float*)d_in[6];
  const float* f1_w = (const float*)d_in[7];
  const float* f1_b = (const float*)d_in[8];
  const float* c1_w = (const float*)d_in[9];
  const float* c1_b = (const float*)d_in[10];
  const float* f2_w = (const float*)d_in[11];
  const float* f2_b = (const float*)d_in[12];
  const float* c2_w = (const float*)d_in[13];
  const float* c2_b = (const float*)d_in[14];
  const float* bnf_g = (const float*)d_in[15];
  const float* bnf_b = (const float*)d_in[16];
  const float* bnc_g = (const float*)d_in[17];
  const float* bnc_b = (const float*)d_in[18];
  const float* bno_g = (const float*)d_in[19];
  const float* bno_b = (const float*)d_in[20];
  const float* l2_w = (const float*)d_in[21];
  const float* l2_b = (const float*)d_in[22];
  const float* out_w = (const float*)d_in[23];
  const float* out_b = (const float*)d_in[24];

  // workspace layout (bytes, 256-aligned)
  char* base = (char*)d_ws;
  size_t off = 0;
  auto alloc = [&](size_t bytes) {
    size_t o = off;
    off = (off + bytes + 255) & ~(size_t)255;
    return o;
  };
  float* xbuf = (float*)(base + alloc((size_t)N_NODES * 64 * 4));
  float* obuf = (float*)(base + alloc((size_t)N_NODES * 64 * 4));
  float* hxVf = (float*)(base + alloc((size_t)N_HEDGES * 64 * 4));  // hx, later Vf
  float* Vc = (float*)(base + alloc((size_t)N_HEDGES * 64 * 4));
  float* ha0 = (float*)(base + alloc((size_t)N_HEDGES * 35 * 4));
  float* Uf = (float*)(base + alloc((size_t)N_NODES * 64 * 4));
  float* Uc = (float*)(base + alloc((size_t)N_NODES * 64 * 4));
  float* invh = (float*)(base + alloc((size_t)N_HEDGES * 4));
  float* invn = (float*)(base + alloc((size_t)N_NODES * 4));
  float* hstats = (float*)(base + alloc(140 * 4));
  float* ostats = (float*)(base + alloc(128 * 4));
  float* pooled = (float*)(base + alloc((size_t)N_GRAPHS * 64 * 4));
  float* gcnt = (float*)(base + alloc((size_t)N_GRAPHS * 4));
  (void)ws_size;
  (void)in_sizes;
  (void)n_in;
  (void)out_size;

  // counts (fixed across layers)
  hipMemsetAsync(invh, 0, (size_t)N_HEDGES * 4, stream);
  hipMemsetAsync(invn, 0, (size_t)N_NODES * 4, stream);
  k_count<<<(N_INC + 255) / 256, 256, 0, stream>>>(node_idx, hedge_idx, invh, invn);
  k_invert<<<(N_HEDGES + 255) / 256, 256, 0, stream>>>(invh, N_HEDGES);
  k_invert<<<(N_NODES + 255) / 256, 256, 0, stream>>>(invn, N_NODES);

  // embed
  k_embed<<<N_NODES / 16, 256, 0, stream>>>(x_in, embed_w, embed_b, xbuf);

  for (int i = 0; i < 3; ++i) {
    const float* ha_in = (i == 0) ? hedge_attr : ha0;
    float* ha_out = ha0;

    // hedge aggregation
    hipMemsetAsync(hxVf, 0, (size_t)N_HEDGES * 64 * 4, stream);
    k_scatter_hx<<<N_INC * 64 / 256, 256, 0, stream>>>(xbuf, node_idx, hedge_idx, hxVf);

    // hedge matvec + BN (stats pass, then apply pass)
    hipMemsetAsync(hstats, 0, 140 * 4, stream);
    k_hedge<1><<<N_HEDGES / HB, 256, 0, stream>>>(
        hxVf, invh, ha_in, f1_w + i * CAT * HE, f1_b + i * HE, c1_w + i * CAT * HE,
        c1_b + i * HE, bnf_g + i * HE, bnf_b + i * HE, bnc_g + i * HE, bnc_b + i * HE,
        hstats, ha_out);
    k_hedge<2><<<N_HEDGES / HB, 256, 0, stream>>>(
        hxVf, invh, ha_in, f1_w + i * CAT * HE, f1_b + i * HE, c1_w + i * CAT * HE,
        c1_b + i * HE, bnf_g + i * HE, bnf_b + i * HE, bnc_g + i * HE, bnc_b + i * HE,
        hstats, ha_out);

    // node/hedge projections (linearity split of the per-incidence matmul)
    k_uv_node<<<N_NODES / 16, 256, 0, stream>>>(xbuf, f2_w + i * CAT * 64,
                                                c2_w + i * CAT * 64, Uf, Uc);
    k_uv_hedge<<<N_HEDGES / 16, 256, 0, stream>>>(
        ha_out, f2_w + i * CAT * 64 + 64 * 64, c2_w + i * CAT * 64 + 64 * 64,
        f2_b + i * 64, c2_b + i * 64, hxVf /*Vf*/, Vc);

    // per-incidence combine + scatter into nodes
    hipMemsetAsync(obuf, 0, (size_t)N_NODES * 64 * 4, stream);
    hipMemsetAsync(ostats, 0, 128 * 4, stream);
    k_inc2<<<N_INC * 64 / 256, 256, 0, stream>>>(node_idx, hedge_idx, Uf, Uc,
                                                 hxVf /*Vf*/, Vc, obuf);

    // node BN + residual softplus
    k_ostats<<<1024, 256, 0, stream>>>(obuf, invn, ostats);
    k_update<<<N_NODES * 64 / 256, 256, 0, stream>>>(xbuf, obuf, invn, ostats,
                                                     bno_g + i * 64, bno_b + i * 64);
  }

  // pooling + head
  hipMemsetAsync(pooled, 0, (size_t)N_GRAPHS * 64 * 4, stream);
  hipMemsetAsync(gcnt, 0, (size_t)N_GRAPHS * 4, stream);
  k_pool<<<N_NODES * 64 / 256, 256, 0, stream>>>(xbuf, batch, pooled, gcnt);
  k_final<<<N_GRAPHS, 128, 0, stream>>>(pooled, gcnt, l2_w, l2_b, out_w, out_b,
                                        (float*)d_out);
}

// Round 2
// 3542.244 us; speedup vs baseline: 1.1529x; 1.1529x over previous
//
#include <hip/hip_runtime.h>
#include <math.h>

#define N_NODES 100000
#define N_HEDGES 200000
#define N_INC 1000000
#define N_GRAPHS 256
#define HD 64
#define HE 35
#define CAT 99
#define EPSB 1e-5f

__device__ __forceinline__ float sp_f(float x) {
  // jax.nn.softplus = max(x,0) + log1p(exp(-|x|))
  return fmaxf(x, 0.f) + log1pf(expf(-fabsf(x)));
}
__device__ __forceinline__ float sig_f(float x) {
  return 1.f / (1.f + expf(-x));
}

// -------------------- int degree histogram --------------------
__global__ __launch_bounds__(256) void k_hist(const int* __restrict__ nidx,
                                              const int* __restrict__ hidx,
                                              int* __restrict__ degN,
                                              int* __restrict__ degH) {
  int e = blockIdx.x * 256 + threadIdx.x;
  if (e >= N_INC) return;
  atomicAdd(&degH[hidx[e]], 1);
  atomicAdd(&degN[nidx[e]], 1);
}

// ---- CSR offsets: block inclusive scan + one global atomic base per block ----
// (segment slices need not be in order -> no global scan needed)
__global__ __launch_bounds__(256) void k_alloc(const int* __restrict__ deg, int n,
                                               int* __restrict__ off,
                                               int* __restrict__ cur,
                                               int* __restrict__ gctr) {
  __shared__ int s[256];
  __shared__ int base;
  int t = threadIdx.x;
  int i = blockIdx.x * 256 + t;
  int d = (i < n) ? deg[i] : 0;
  s[t] = d;
  __syncthreads();
  for (int st = 1; st < 256; st <<= 1) {
    int u = 0;
    if (t >= st) u = s[t - st];
    __syncthreads();
    if (t >= st) s[t] += u;
    __syncthreads();
  }
  if (t == 255) base = atomicAdd(gctr, s[255]);
  __syncthreads();
  int ex = s[t] - d + base;
  if (i < n) {
    off[i] = ex;
    cur[i] = ex;
  }
}

__global__ __launch_bounds__(256) void k_fill(const int* __restrict__ nidx,
                                              const int* __restrict__ hidx,
                                              int* __restrict__ curH,
                                              int* __restrict__ curN,
                                              int* __restrict__ permHn,
                                              int* __restrict__ permNh) {
  int e = blockIdx.x * 256 + threadIdx.x;
  if (e >= N_INC) return;
  int nd = nidx[e], hg = hidx[e];
  int p = atomicAdd(&curH[hg], 1);
  permHn[p] = nd;
  int q = atomicAdd(&curN[nd], 1);
  permNh[q] = hg;
}

// -------------------- embed: x[N,92] @ w[92,64] + b --------------------
__global__ __launch_bounds__(256) void k_embed(const float* __restrict__ x,
                                               const float* __restrict__ w,
                                               const float* __restrict__ b,
                                               float* __restrict__ out) {
  __shared__ float ws[92 * 64];
  __shared__ float rs[16][93];
  int tid = threadIdx.x;
  for (int i = tid; i < 92 * 64; i += 256) ws[i] = w[i];
  int r0 = blockIdx.x * 16;
  for (int i = tid; i < 16 * 92; i += 256) {
    int r = i / 92, k = i - r * 92;
    rs[r][k] = x[(r0 + r) * 92 + k];
  }
  __syncthreads();
  int h = tid & 63;
  float bias = b[h];
  for (int rr = tid >> 6; rr < 16; rr += 4) {
    float acc = bias;
    for (int k = 0; k < 92; ++k) acc += rs[rr][k] * ws[k * 64 + h];
    out[(r0 + rr) * 64 + h] = acc;
  }
}

// --------- hedge gather-mean via CSR: one wave per hedge, lane=feature ---------
__global__ __launch_bounds__(256) void k_gather_hx(const float* __restrict__ x,
                                                   const int* __restrict__ permHn,
                                                   const int* __restrict__ offH,
                                                   const int* __restrict__ degH,
                                                   float* __restrict__ hx) {
  int gt = blockIdx.x * 256 + threadIdx.x;
  int wid = gt >> 6, h = gt & 63;
  if (wid >= N_HEDGES) return;
  int o = offH[wid], d = degH[wid];
  float acc = 0.f;
  for (int k = 0; k < d; ++k) {
    int nd = permHn[o + k];
    acc += x[nd * 64 + h];
  }
  hx[wid * 64 + h] = acc / (float)max(d, 1);
}

// -------------------- hedge matvec + BN (two passes) --------------------
#define HB 32
template <int PASS>
__global__ __launch_bounds__(256) void k_hedge(
    const float* __restrict__ hx, const float* __restrict__ ha_in,
    const float* __restrict__ w_f, const float* __restrict__ b_f,
    const float* __restrict__ w_c, const float* __restrict__ b_c,
    const float* __restrict__ gf, const float* __restrict__ bf_,
    const float* __restrict__ gc, const float* __restrict__ bc_,
    float* __restrict__ stats, float* __restrict__ ha_out) {
  __shared__ float wf[CAT * HE];
  __shared__ float wc[CAT * HE];
  __shared__ float msg[HB][CAT + 1];
  __shared__ float ps[140];
  int tid = threadIdx.x;
  for (int i = tid; i < CAT * HE; i += 256) {
    wf[i] = w_f[i];
    wc[i] = w_c[i];
  }
  if (PASS == 1)
    for (int i = tid; i < 140; i += 256) ps[i] = 0.f;
  int j0 = blockIdx.x * HB;
  for (int i = tid; i < HB * CAT; i += 256) {
    int r = i / CAT, k = i - r * CAT;
    int j = j0 + r;
    msg[r][k] = (k < HD) ? hx[j * HD + k] : ha_in[j * HE + (k - HD)];
  }
  __syncthreads();
  for (int p = tid; p < HB * HE; p += 256) {
    int r = p / HE, c = p - r * HE;
    float zf = b_f[c], zc = b_c[c];
    const float* m = msg[r];
    for (int k = 0; k < CAT; ++k) {
      float v = m[k];
      zf += v * wf[k * HE + c];
      zc += v * wc[k * HE + c];
    }
    if (PASS == 1) {
      atomicAdd(&ps[c], zf);
      atomicAdd(&ps[35 + c], zf * zf);
      atomicAdd(&ps[70 + c], zc);
      atomicAdd(&ps[105 + c], zc * zc);
    } else {
      float mf = stats[c] * (1.f / N_HEDGES);
      float vf = stats[35 + c] * (1.f / N_HEDGES) - mf * mf;
      float mc = stats[70 + c] * (1.f / N_HEDGES);
      float vc = stats[105 + c] * (1.f / N_HEDGES) - mc * mc;
      float nf = (zf - mf) * rsqrtf(vf + EPSB) * gf[c] + bf_[c];
      float nc = (zc - mc) * rsqrtf(vc + EPSB) * gc[c] + bc_[c];
      ha_out[(j0 + r) * HE + c] = sig_f(nf) * sp_f(nc);
    }
  }
  if (PASS == 1) {
    __syncthreads();
    if (tid < 140) atomicAdd(&stats[tid], ps[tid]);
  }
}

// ---------- per-node projection: U = x @ W[0:64,:] (k-outer, weight reuse) ----------
__global__ __launch_bounds__(256) void k_uv_node(const float* __restrict__ x,
                                                 const float* __restrict__ f2w,
                                                 const float* __restrict__ c2w,
                                                 float* __restrict__ Uf,
                                                 float* __restrict__ Uc) {
  __shared__ float wf[64 * 64];
  __shared__ float wc[64 * 64];
  __shared__ float rs[16][65];
  int tid = threadIdx.x;
  for (int i = tid; i < 64 * 64; i += 256) {
    wf[i] = f2w[i];
    wc[i] = c2w[i];
  }
  int r0 = blockIdx.x * 16;
  for (int i = tid; i < 16 * 64; i += 256) {
    int r = i >> 6, k = i & 63;
    rs[r][k] = x[(r0 + r) * 64 + k];
  }
  __syncthreads();
  int h = tid & 63, rb = tid >> 6;
  float af0 = 0, af1 = 0, af2 = 0, af3 = 0, ac0 = 0, ac1 = 0, ac2 = 0, ac3 = 0;
  for (int k = 0; k < 64; ++k) {
    float wfv = wf[k * 64 + h], wcv = wc[k * 64 + h];
    float m0 = rs[rb][k], m1 = rs[rb + 4][k], m2 = rs[rb + 8][k], m3 = rs[rb + 12][k];
    af0 += m0 * wfv; ac0 += m0 * wcv;
    af1 += m1 * wfv; ac1 += m1 * wcv;
    af2 += m2 * wfv; ac2 += m2 * wcv;
    af3 += m3 * wfv; ac3 += m3 * wcv;
  }
  int row = r0 + rb;
  Uf[row * 64 + h] = af0;          Uc[row * 64 + h] = ac0;
  Uf[(row + 4) * 64 + h] = af1;    Uc[(row + 4) * 64 + h] = ac1;
  Uf[(row + 8) * 64 + h] = af2;    Uc[(row + 8) * 64 + h] = ac2;
  Uf[(row + 12) * 64 + h] = af3;   Uc[(row + 12) * 64 + h] = ac3;
}

// ---------------- per-hedge projection: V = ha @ W[64:99,:] + bias ----------------
__global__ __launch_bounds__(256) void k_uv_hedge(const float* __restrict__ ha,
                                                  const float* __restrict__ f2wb,
                                                  const float* __restrict__ c2wb,
                                                  const float* __restrict__ f2b,
                                                  const float* __restrict__ c2b,
                                                  float* __restrict__ Vf,
                                                  float* __restrict__ Vc) {
  __shared__ float wf[35 * 64];
  __shared__ float wc[35 * 64];
  __shared__ float rs[16][36];
  int tid = threadIdx.x;
  for (int i = tid; i < 35 * 64; i += 256) {
    wf[i] = f2wb[i];
    wc[i] = c2wb[i];
  }
  int r0 = blockIdx.x * 16;
  for (int i = tid; i < 16 * 35; i += 256) {
    int r = i / 35, k = i - r * 35;
    rs[r][k] = ha[(r0 + r) * 35 + k];
  }
  __syncthreads();
  int h = tid & 63, rb = tid >> 6;
  float af0, af1, af2, af3, ac0, ac1, ac2, ac3;
  af0 = af1 = af2 = af3 = f2b[h];
  ac0 = ac1 = ac2 = ac3 = c2b[h];
  for (int k = 0; k < 35; ++k) {
    float wfv = wf[k * 64 + h], wcv = wc[k * 64 + h];
    float m0 = rs[rb][k], m1 = rs[rb + 4][k], m2 = rs[rb + 8][k], m3 = rs[rb + 12][k];
    af0 += m0 * wfv; ac0 += m0 * wcv;
    af1 += m1 * wfv; ac1 += m1 * wcv;
    af2 += m2 * wfv; ac2 += m2 * wcv;
    af3 += m3 * wfv; ac3 += m3 * wcv;
  }
  int row = r0 + rb;
  Vf[row * 64 + h] = af0;          Vc[row * 64 + h] = ac0;
  Vf[(row + 4) * 64 + h] = af1;    Vc[(row + 4) * 64 + h] = ac1;
  Vf[(row + 8) * 64 + h] = af2;    Vc[(row + 8) * 64 + h] = ac2;
  Vf[(row + 12) * 64 + h] = af3;   Vc[(row + 12) * 64 + h] = ac3;
}

// ------ per-node aggregate via CSR: o[n] = mean_e sig(U+V)*sp(U+V), no atomics ------
__global__ __launch_bounds__(256) void k_node_aggr(const int* __restrict__ permNh,
                                                   const int* __restrict__ offN,
                                                   const int* __restrict__ degN,
                                                   const float* __restrict__ Uf,
                                                   const float* __restrict__ Uc,
                                                   const float* __restrict__ Vf,
                                                   const float* __restrict__ Vc,
                                                   float* __restrict__ o) {
  int gt = blockIdx.x * 256 + threadIdx.x;
  int wid = gt >> 6, h = gt & 63;
  if (wid >= N_NODES) return;
  int off = offN[wid], d = degN[wid];
  float uf = Uf[wid * 64 + h], uc = Uc[wid * 64 + h];
  float acc = 0.f;
  for (int k = 0; k < d; ++k) {
    int hg = permNh[off + k];
    acc += sig_f(uf + Vf[hg * 64 + h]) * sp_f(uc + Vc[hg * 64 + h]);
  }
  o[wid * 64 + h] = acc / (float)max(d, 1);
}

// -------------------- BN stats over node features (o pre-scaled) --------------------
__global__ __launch_bounds__(256) void k_ostats(const float* __restrict__ o,
                                                float* __restrict__ stats) {
  int h = threadIdx.x & 63;
  int rs = threadIdx.x >> 6;
  float s = 0.f, sq = 0.f;
  for (int r = blockIdx.x * 4 + rs; r < N_NODES; r += gridDim.x * 4) {
    float v = o[r * 64 + h];
    s += v;
    sq += v * v;
  }
  __shared__ float ls[4][2][64];
  ls[rs][0][h] = s;
  ls[rs][1][h] = sq;
  __syncthreads();
  if (threadIdx.x < 64) {
    float ts = ls[0][0][h] + ls[1][0][h] + ls[2][0][h] + ls[3][0][h];
    float tq = ls[0][1][h] + ls[1][1][h] + ls[2][1][h] + ls[3][1][h];
    atomicAdd(&stats[h], ts);
    atomicAdd(&stats[64 + h], tq);
  }
}

// -------------------- x = softplus(BN(o_mean) + x) --------------------
__global__ __launch_bounds__(256) void k_update(float* __restrict__ x,
                                                const float* __restrict__ o,
                                                const float* __restrict__ stats,
                                                const float* __restrict__ g,
                                                const float* __restrict__ b) {
  int t = blockIdx.x * 256 + threadIdx.x;  // N*64
  int h = t & 63;
  float mean = stats[h] * (1.f / N_NODES);
  float var = stats[64 + h] * (1.f / N_NODES) - mean * mean;
  float is = rsqrtf(var + EPSB);
  float v = (o[t] - mean) * is * g[h] + b[h];
  x[t] = sp_f(v + x[t]);
}

// ------- graph pooling: chunked register accumulation (batch is sorted) -------
#define PR 512
__global__ __launch_bounds__(256) void k_pool(const float* __restrict__ x,
                                              const int* __restrict__ batch,
                                              float* __restrict__ pooled,
                                              float* __restrict__ gcnt) {
  int h = threadIdx.x & 63, rs = threadIdx.x >> 6;
  int r0 = blockIdx.x * PR;
  int rend = min(r0 + PR, N_NODES);
  int gcur = -1;
  float acc = 0.f;
  int cnt = 0;
  for (int r = r0 + rs; r < rend; r += 4) {
    int g = batch[r];
    if (g != gcur) {
      if (gcur >= 0) {
        atomicAdd(&pooled[gcur * 64 + h], acc);
        if (h == 0) atomicAdd(&gcnt[gcur], (float)cnt);
      }
      gcur = g;
      acc = 0.f;
      cnt = 0;
    }
    acc += x[r * 64 + h];
    cnt++;
  }
  if (gcur >= 0) {
    atomicAdd(&pooled[gcur * 64 + h], acc);
    if (h == 0) atomicAdd(&gcnt[gcur], (float)cnt);
  }
}

// -------------------- final dense layers --------------------
__global__ __launch_bounds__(128) void k_final(const float* __restrict__ pooled,
                                               const float* __restrict__ gcnt,
                                               const float* __restrict__ l2w,
                                               const float* __restrict__ l2b,
                                               const float* __restrict__ ow,
                                               const float* __restrict__ ob,
                                               float* __restrict__ out) {
  int g = blockIdx.x;
  int t = threadIdx.x;
  __shared__ float row[64];
  __shared__ float hh[128];
  if (t < 64) row[t] = pooled[g * 64 + t] / fmaxf(gcnt[g], 1.f);
  __syncthreads();
  float acc = l2b[t];
  for (int k = 0; k < 64; ++k) acc += row[k] * l2w[k * 128 + t];
  hh[t] = sp_f(acc) * ow[t];
  __syncthreads();
  for (int s = 64; s > 0; s >>= 1) {
    if (t < s) hh[t] += hh[t + s];
    __syncthreads();
  }
  if (t == 0) out[g] = hh[0] + ob[0];
}

extern "C" void kernel_launch(void* const* d_in, const int* in_sizes, int n_in,
                              void* d_out, int out_size, void* d_ws, size_t ws_size,
                              hipStream_t stream) {
  const float* x_in = (const float*)d_in[0];
  const int* node_idx = (const int*)d_in[1];
  const int* hedge_idx = (const int*)d_in[2];
  const float* hedge_attr = (const float*)d_in[3];
  const int* batch = (const int*)d_in[4];
  const float* embed_w = (const float*)d_in[5];
  const float* embed_b = (const float*)d_in[6];
  const float* f1_w = (const float*)d_in[7];
  const float* f1_b = (const float*)d_in[8];
  const float* c1_w = (const float*)d_in[9];
  const float* c1_b = (const float*)d_in[10];
  const float* f2_w = (const float*)d_in[11];
  const float* f2_b = (const float*)d_in[12];
  const float* c2_w = (const float*)d_in[13];
  const float* c2_b = (const float*)d_in[14];
  const float* bnf_g = (const float*)d_in[15];
  const float* bnf_b = (const float*)d_in[16];
  const float* bnc_g = (const float*)d_in[17];
  const float* bnc_b = (const float*)d_in[18];
  const float* bno_g = (const float*)d_in[19];
  const float* bno_b = (const float*)d_in[20];
  const float* l2_w = (const float*)d_in[21];
  const float* l2_b = (const float*)d_in[22];
  const float* out_w = (const float*)d_in[23];
  const float* out_b = (const float*)d_in[24];

  // workspace layout (bytes, 256-aligned)
  char* base = (char*)d_ws;
  size_t off = 0;
  auto alloc = [&](size_t bytes) {
    size_t o = off;
    off = (off + bytes + 255) & ~(size_t)255;
    return o;
  };
  float* xbuf = (float*)(base + alloc((size_t)N_NODES * 64 * 4));
  float* obuf = (float*)(base + alloc((size_t)N_NODES * 64 * 4));
  float* hxVf = (float*)(base + alloc((size_t)N_HEDGES * 64 * 4));  // hx, later Vf
  float* Vc = (float*)(base + alloc((size_t)N_HEDGES * 64 * 4));
  float* ha0 = (float*)(base + alloc((size_t)N_HEDGES * 35 * 4));
  float* Uf = (float*)(base + alloc((size_t)N_NODES * 64 * 4));
  float* Uc = (float*)(base + alloc((size_t)N_NODES * 64 * 4));
  float* hstats = (float*)(base + alloc(140 * 4));
  float* ostats = (float*)(base + alloc(128 * 4));
  float* pooled = (float*)(base + alloc((size_t)N_GRAPHS * 64 * 4));
  float* gcnt = (float*)(base + alloc((size_t)N_GRAPHS * 4));
  int* degH = (int*)(base + alloc((size_t)N_HEDGES * 4));
  int* offH = (int*)(base + alloc((size_t)N_HEDGES * 4));
  int* curH = (int*)(base + alloc((size_t)N_HEDGES * 4));
  int* degN = (int*)(base + alloc((size_t)N_NODES * 4));
  int* offN = (int*)(base + alloc((size_t)N_NODES * 4));
  int* curN = (int*)(base + alloc((size_t)N_NODES * 4));
  int* permHn = (int*)(base + alloc((size_t)N_INC * 4));
  int* permNh = (int*)(base + alloc((size_t)N_INC * 4));
  int* gctr = (int*)(base + alloc(2 * 4));
  (void)ws_size;
  (void)in_sizes;
  (void)n_in;
  (void)out_size;

  // ---- CSR build (once; index lists are call-invariant) ----
  hipMemsetAsync(degH, 0, (size_t)N_HEDGES * 4, stream);
  hipMemsetAsync(degN, 0, (size_t)N_NODES * 4, stream);
  hipMemsetAsync(gctr, 0, 2 * 4, stream);
  k_hist<<<(N_INC + 255) / 256, 256, 0, stream>>>(node_idx, hedge_idx, degN, degH);
  k_alloc<<<(N_HEDGES + 255) / 256, 256, 0, stream>>>(degH, N_HEDGES, offH, curH, &gctr[0]);
  k_alloc<<<(N_NODES + 255) / 256, 256, 0, stream>>>(degN, N_NODES, offN, curN, &gctr[1]);
  k_fill<<<(N_INC + 255) / 256, 256, 0, stream>>>(node_idx, hedge_idx, curH, curN,
                                                  permHn, permNh);

  // embed
  k_embed<<<N_NODES / 16, 256, 0, stream>>>(x_in, embed_w, embed_b, xbuf);

  for (int i = 0; i < 3; ++i) {
    const float* ha_in = (i == 0) ? hedge_attr : ha0;
    float* ha_out = ha0;

    // hedge aggregation (CSR gather, mean folded in)
    k_gather_hx<<<N_HEDGES * 64 / 256, 256, 0, stream>>>(xbuf, permHn, offH, degH, hxVf);

    // hedge matvec + BN (stats pass, then apply pass)
    hipMemsetAsync(hstats, 0, 140 * 4, stream);
    k_hedge<1><<<N_HEDGES / HB, 256, 0, stream>>>(
        hxVf, ha_in, f1_w + i * CAT * HE, f1_b + i * HE, c1_w + i * CAT * HE,
        c1_b + i * HE, bnf_g + i * HE, bnf_b + i * HE, bnc_g + i * HE, bnc_b + i * HE,
        hstats, ha_out);
    k_hedge<2><<<N_HEDGES / HB, 256, 0, stream>>>(
        hxVf, ha_in, f1_w + i * CAT * HE, f1_b + i * HE, c1_w + i * CAT * HE,
        c1_b + i * HE, bnf_g + i * HE, bnf_b + i * HE, bnc_g + i * HE, bnc_b + i * HE,
        hstats, ha_out);

    // node/hedge projections (linearity split of the per-incidence matmul)
    k_uv_node<<<N_NODES / 16, 256, 0, stream>>>(xbuf, f2_w + i * CAT * 64,
                                                c2_w + i * CAT * 64, Uf, Uc);
    k_uv_hedge<<<N_HEDGES / 16, 256, 0, stream>>>(
        ha_out, f2_w + i * CAT * 64 + 64 * 64, c2_w + i * CAT * 64 + 64 * 64,
        f2_b + i * 64, c2_b + i * 64, hxVf /*Vf*/, Vc);

    // per-node combine via CSR (no atomics, mean folded in)
    k_node_aggr<<<N_NODES * 64 / 256, 256, 0, stream>>>(permNh, offN, degN, Uf, Uc,
                                                        hxVf /*Vf*/, Vc, obuf);

    // node BN + residual softplus
    hipMemsetAsync(ostats, 0, 128 * 4, stream);
    k_ostats<<<1024, 256, 0, stream>>>(obuf, ostats);
    k_update<<<N_NODES * 64 / 256, 256, 0, stream>>>(xbuf, obuf, ostats,
                                                     bno_g + i * 64, bno_b + i * 64);
  }

  // pooling + head
  hipMemsetAsync(pooled, 0, (size_t)N_GRAPHS * 64 * 4, stream);
  hipMemsetAsync(gcnt, 0, (size_t)N_GRAPHS * 4, stream);
  k_pool<<<(N_NODES + PR - 1) / PR, 256, 0, stream>>>(xbuf, batch, pooled, gcnt);
  k_final<<<N_GRAPHS, 128, 0, stream>>>(pooled, gcnt, l2_w, l2_b, out_w, out_b,
                                        (float*)d_out);
}

// Round 3
// 2467.409 us; speedup vs baseline: 1.6551x; 1.4356x over previous
//
#include <hip/hip_runtime.h>
#include <math.h>

#define N_NODES 100000
#define N_HEDGES 200000
#define N_INC 1000000
#define N_GRAPHS 256
#define HD 64
#define HE 35
#define CAT 99
#define EPSB 1e-5f

__device__ __forceinline__ float sp_f(float x) {
  // jax.nn.softplus = max(x,0) + log1p(exp(-|x|))
  return fmaxf(x, 0.f) + log1pf(expf(-fabsf(x)));
}
__device__ __forceinline__ float sig_f(float x) {
  return 1.f / (1.f + expf(-x));
}

// -------------------- int degree histogram --------------------
__global__ __launch_bounds__(256) void k_hist(const int* __restrict__ nidx,
                                              const int* __restrict__ hidx,
                                              int* __restrict__ degN,
                                              int* __restrict__ degH) {
  int e = blockIdx.x * 256 + threadIdx.x;
  if (e >= N_INC) return;
  atomicAdd(&degH[hidx[e]], 1);
  atomicAdd(&degN[nidx[e]], 1);
}

// ---- CSR offsets: block inclusive scan + one global atomic base per block ----
__global__ __launch_bounds__(256) void k_alloc(const int* __restrict__ deg, int n,
                                               int* __restrict__ off,
                                               int* __restrict__ cur,
                                               int* __restrict__ gctr) {
  __shared__ int s[256];
  __shared__ int base;
  int t = threadIdx.x;
  int i = blockIdx.x * 256 + t;
  int d = (i < n) ? deg[i] : 0;
  s[t] = d;
  __syncthreads();
  for (int st = 1; st < 256; st <<= 1) {
    int u = 0;
    if (t >= st) u = s[t - st];
    __syncthreads();
    if (t >= st) s[t] += u;
    __syncthreads();
  }
  if (t == 255) base = atomicAdd(gctr, s[255]);
  __syncthreads();
  int ex = s[t] - d + base;
  if (i < n) {
    off[i] = ex;
    cur[i] = ex;
  }
}

__global__ __launch_bounds__(256) void k_fill(const int* __restrict__ nidx,
                                              const int* __restrict__ hidx,
                                              int* __restrict__ curH,
                                              int* __restrict__ curN,
                                              int* __restrict__ permHn,
                                              int* __restrict__ permNh) {
  int e = blockIdx.x * 256 + threadIdx.x;
  if (e >= N_INC) return;
  int nd = nidx[e], hg = hidx[e];
  int p = atomicAdd(&curH[hg], 1);
  permHn[p] = nd;
  int q = atomicAdd(&curN[nd], 1);
  permNh[q] = hg;
}

// -------------------- embed: x[N,92] @ w[92,64] + b --------------------
__global__ __launch_bounds__(256) void k_embed(const float* __restrict__ x,
                                               const float* __restrict__ w,
                                               const float* __restrict__ b,
                                               float* __restrict__ out) {
  __shared__ float ws[92 * 64];
  __shared__ float rs[16][93];
  int tid = threadIdx.x;
  for (int i = tid; i < 92 * 64; i += 256) ws[i] = w[i];
  int r0 = blockIdx.x * 16;
  for (int i = tid; i < 16 * 92; i += 256) {
    int r = i / 92, k = i - r * 92;
    rs[r][k] = x[(r0 + r) * 92 + k];
  }
  __syncthreads();
  int h = tid & 63;
  float bias = b[h];
  for (int rr = tid >> 6; rr < 16; rr += 4) {
    float acc = bias;
    for (int k = 0; k < 92; ++k) acc += rs[rr][k] * ws[k * 64 + h];
    out[(r0 + rr) * 64 + h] = acc;
  }
}

// --------- hedge gather-mean via CSR: one wave per hedge, lane=feature ---------
__global__ __launch_bounds__(256) void k_gather_hx(const float* __restrict__ x,
                                                   const int* __restrict__ permHn,
                                                   const int* __restrict__ offH,
                                                   const int* __restrict__ degH,
                                                   float* __restrict__ hx) {
  int gt = blockIdx.x * 256 + threadIdx.x;
  int wid = gt >> 6, h = gt & 63;
  if (wid >= N_HEDGES) return;
  int o = offH[wid], d = degH[wid];
  float acc = 0.f;
  for (int k = 0; k < d; ++k) {
    int nd = permHn[o + k];
    acc += x[nd * 64 + h];
  }
  hx[wid * 64 + h] = acc / (float)max(d, 1);
}

// ------ hedge GEMM, single pass: Z[r][72] = msg[r][99] @ [Wf|Wc], + col stats ------
// tile: 112 rows x 72 cols (f 0..35, c 36..71; col 35/71 are zero-padding).
// thread t<252: col-slot s = t%18 (cols s, s+18 of each half), row-group rg = t/18 (8 rows).
#define HROWS 112
#define HSTR 100  // padded k-stride (25 float4)
__global__ __launch_bounds__(256) void k_hedge_gemm(
    const float* __restrict__ hx, const float* __restrict__ ha_in,
    const float* __restrict__ w_f, const float* __restrict__ w_c,
    float* __restrict__ z, float* __restrict__ stats) {
  __shared__ float wfT[36 * HSTR];
  __shared__ float wcT[36 * HSTR];
  __shared__ float msg[HROWS * HSTR];
  __shared__ float ps[144];
  int tid = threadIdx.x;
  // weights transposed: wfT[c*HSTR + k] = w_f[k*35 + c]; zero-pad c=35, k=99
  for (int i = tid; i < 36 * HSTR; i += 256) {
    int c = i / HSTR, k = i - c * HSTR;
    float vf = 0.f, vc = 0.f;
    if (c < 35 && k < 99) {
      vf = w_f[k * 35 + c];
      vc = w_c[k * 35 + c];
    }
    wfT[i] = vf;
    wcT[i] = vc;
  }
  if (tid < 144) ps[tid] = 0.f;
  int r0 = blockIdx.x * HROWS;
  for (int i = tid; i < HROWS * HSTR; i += 256) {
    int r = i / HSTR, k = i - r * HSTR;
    int row = r0 + r;
    float v = 0.f;
    if (row < N_HEDGES) {
      if (k < 64)
        v = hx[row * 64 + k];
      else if (k < 99)
        v = ha_in[row * 35 + (k - 64)];
    }
    msg[i] = v;
  }
  __syncthreads();
  if (tid < 252) {
    int s = tid % 18, rg = tid / 18;
    float accf0[8], accf1[8], accc0[8], accc1[8];
#pragma unroll
    for (int j = 0; j < 8; ++j) accf0[j] = accf1[j] = accc0[j] = accc1[j] = 0.f;
    const float4* wf0p = (const float4*)&wfT[s * HSTR];
    const float4* wf1p = (const float4*)&wfT[(s + 18) * HSTR];
    const float4* wc0p = (const float4*)&wcT[s * HSTR];
    const float4* wc1p = (const float4*)&wcT[(s + 18) * HSTR];
    for (int kk = 0; kk < 25; ++kk) {
      float4 wf0 = wf0p[kk], wf1 = wf1p[kk], wc0 = wc0p[kk], wc1 = wc1p[kk];
#pragma unroll
      for (int j = 0; j < 8; ++j) {
        float4 m = ((const float4*)&msg[(rg * 8 + j) * HSTR])[kk];
        accf0[j] += m.x * wf0.x + m.y * wf0.y + m.z * wf0.z + m.w * wf0.w;
        accf1[j] += m.x * wf1.x + m.y * wf1.y + m.z * wf1.z + m.w * wf1.w;
        accc0[j] += m.x * wc0.x + m.y * wc0.y + m.z * wc0.z + m.w * wc0.w;
        accc1[j] += m.x * wc1.x + m.y * wc1.y + m.z * wc1.z + m.w * wc1.w;
      }
    }
    float sf0 = 0, qf0 = 0, sf1 = 0, qf1 = 0, sc0 = 0, qc0 = 0, sc1 = 0, qc1 = 0;
#pragma unroll
    for (int j = 0; j < 8; ++j) {
      int row = r0 + rg * 8 + j;
      if (row < N_HEDGES) {
        float zf0 = accf0[j], zf1 = accf1[j], zc0 = accc0[j], zc1 = accc1[j];
        float* zr = &z[(size_t)row * 72];
        zr[s] = zf0;
        zr[s + 18] = zf1;
        zr[36 + s] = zc0;
        zr[54 + s] = zc1;
        sf0 += zf0; qf0 += zf0 * zf0;
        sf1 += zf1; qf1 += zf1 * zf1;
        sc0 += zc0; qc0 += zc0 * zc0;
        sc1 += zc1; qc1 += zc1 * zc1;
      }
    }
    // stats layout: [0..35]=sum_f [36..71]=sumsq_f [72..107]=sum_c [108..143]=sumsq_c
    atomicAdd(&ps[s], sf0);
    atomicAdd(&ps[s + 18], sf1);
    atomicAdd(&ps[36 + s], qf0);
    atomicAdd(&ps[54 + s], qf1);
    atomicAdd(&ps[72 + s], sc0);
    atomicAdd(&ps[90 + s], sc1);
    atomicAdd(&ps[108 + s], qc0);
    atomicAdd(&ps[126 + s], qc1);
  }
  __syncthreads();
  if (tid < 144) atomicAdd(&stats[tid], ps[tid]);
}

// ---- elementwise BN + sigmoid*softplus over Z -> ha_out[200K][35] ----
__global__ __launch_bounds__(256) void k_hedge_apply(
    const float* __restrict__ z, const float* __restrict__ stats,
    const float* __restrict__ gf, const float* __restrict__ bf_,
    const float* __restrict__ gc, const float* __restrict__ bc_,
    float* __restrict__ ha_out) {
  int t = blockIdx.x * 256 + threadIdx.x;
  if (t >= N_HEDGES * 35) return;
  int r = t / 35, c = t - r * 35;
  float mf = stats[c] * (1.f / N_HEDGES);
  float vf = stats[36 + c] * (1.f / N_HEDGES) - mf * mf;
  float mc = stats[72 + c] * (1.f / N_HEDGES);
  float vc = stats[108 + c] * (1.f / N_HEDGES) - mc * mc;
  const float* zr = &z[(size_t)r * 72];
  float nf = (zr[c] - mf) * rsqrtf(vf + EPSB) * gf[c] + bf_[c];
  float nc = (zr[36 + c] - mc) * rsqrtf(vc + EPSB) * gc[c] + bc_[c];
  ha_out[t] = sig_f(nf) * sp_f(nc);
}

// ---------- per-node projection: U = x @ W[0:64,:] (k-outer, weight reuse) ----------
__global__ __launch_bounds__(256) void k_uv_node(const float* __restrict__ x,
                                                 const float* __restrict__ f2w,
                                                 const float* __restrict__ c2w,
                                                 float* __restrict__ Uf,
                                                 float* __restrict__ Uc) {
  __shared__ float wf[64 * 64];
  __shared__ float wc[64 * 64];
  __shared__ float rs[16][65];
  int tid = threadIdx.x;
  for (int i = tid; i < 64 * 64; i += 256) {
    wf[i] = f2w[i];
    wc[i] = c2w[i];
  }
  int r0 = blockIdx.x * 16;
  for (int i = tid; i < 16 * 64; i += 256) {
    int r = i >> 6, k = i & 63;
    rs[r][k] = x[(r0 + r) * 64 + k];
  }
  __syncthreads();
  int h = tid & 63, rb = tid >> 6;
  float af0 = 0, af1 = 0, af2 = 0, af3 = 0, ac0 = 0, ac1 = 0, ac2 = 0, ac3 = 0;
  for (int k = 0; k < 64; ++k) {
    float wfv = wf[k * 64 + h], wcv = wc[k * 64 + h];
    float m0 = rs[rb][k], m1 = rs[rb + 4][k], m2 = rs[rb + 8][k], m3 = rs[rb + 12][k];
    af0 += m0 * wfv; ac0 += m0 * wcv;
    af1 += m1 * wfv; ac1 += m1 * wcv;
    af2 += m2 * wfv; ac2 += m2 * wcv;
    af3 += m3 * wfv; ac3 += m3 * wcv;
  }
  int row = r0 + rb;
  Uf[row * 64 + h] = af0;          Uc[row * 64 + h] = ac0;
  Uf[(row + 4) * 64 + h] = af1;    Uc[(row + 4) * 64 + h] = ac1;
  Uf[(row + 8) * 64 + h] = af2;    Uc[(row + 8) * 64 + h] = ac2;
  Uf[(row + 12) * 64 + h] = af3;   Uc[(row + 12) * 64 + h] = ac3;
}

// ---------------- per-hedge projection: V = ha @ W[64:99,:] + bias ----------------
__global__ __launch_bounds__(256) void k_uv_hedge(const float* __restrict__ ha,
                                                  const float* __restrict__ f2wb,
                                                  const float* __restrict__ c2wb,
                                                  const float* __restrict__ f2b,
                                                  const float* __restrict__ c2b,
                                                  float* __restrict__ Vf,
                                                  float* __restrict__ Vc) {
  __shared__ float wf[35 * 64];
  __shared__ float wc[35 * 64];
  __shared__ float rs[16][36];
  int tid = threadIdx.x;
  for (int i = tid; i < 35 * 64; i += 256) {
    wf[i] = f2wb[i];
    wc[i] = c2wb[i];
  }
  int r0 = blockIdx.x * 16;
  for (int i = tid; i < 16 * 35; i += 256) {
    int r = i / 35, k = i - r * 35;
    rs[r][k] = ha[(r0 + r) * 35 + k];
  }
  __syncthreads();
  int h = tid & 63, rb = tid >> 6;
  float af0, af1, af2, af3, ac0, ac1, ac2, ac3;
  af0 = af1 = af2 = af3 = f2b[h];
  ac0 = ac1 = ac2 = ac3 = c2b[h];
  for (int k = 0; k < 35; ++k) {
    float wfv = wf[k * 64 + h], wcv = wc[k * 64 + h];
    float m0 = rs[rb][k], m1 = rs[rb + 4][k], m2 = rs[rb + 8][k], m3 = rs[rb + 12][k];
    af0 += m0 * wfv; ac0 += m0 * wcv;
    af1 += m1 * wfv; ac1 += m1 * wcv;
    af2 += m2 * wfv; ac2 += m2 * wcv;
    af3 += m3 * wfv; ac3 += m3 * wcv;
  }
  int row = r0 + rb;
  Vf[row * 64 + h] = af0;          Vc[row * 64 + h] = ac0;
  Vf[(row + 4) * 64 + h] = af1;    Vc[(row + 4) * 64 + h] = ac1;
  Vf[(row + 8) * 64 + h] = af2;    Vc[(row + 8) * 64 + h] = ac2;
  Vf[(row + 12) * 64 + h] = af3;   Vc[(row + 12) * 64 + h] = ac3;
}

// ------ per-node aggregate via CSR: o[n] = mean_e sig(U+V)*sp(U+V), no atomics ------
__global__ __launch_bounds__(256) void k_node_aggr(const int* __restrict__ permNh,
                                                   const int* __restrict__ offN,
                                                   const int* __restrict__ degN,
                                                   const float* __restrict__ Uf,
                                                   const float* __restrict__ Uc,
                                                   const float* __restrict__ Vf,
                                                   const float* __restrict__ Vc,
                                                   float* __restrict__ o) {
  int gt = blockIdx.x * 256 + threadIdx.x;
  int wid = gt >> 6, h = gt & 63;
  if (wid >= N_NODES) return;
  int off = offN[wid], d = degN[wid];
  float uf = Uf[wid * 64 + h], uc = Uc[wid * 64 + h];
  float acc = 0.f;
  for (int k = 0; k < d; ++k) {
    int hg = permNh[off + k];
    acc += sig_f(uf + Vf[hg * 64 + h]) * sp_f(uc + Vc[hg * 64 + h]);
  }
  o[wid * 64 + h] = acc / (float)max(d, 1);
}

// -------------------- BN stats over node features (o pre-scaled) --------------------
__global__ __launch_bounds__(256) void k_ostats(const float* __restrict__ o,
                                                float* __restrict__ stats) {
  int h = threadIdx.x & 63;
  int rs = threadIdx.x >> 6;
  float s = 0.f, sq = 0.f;
  for (int r = blockIdx.x * 4 + rs; r < N_NODES; r += gridDim.x * 4) {
    float v = o[r * 64 + h];
    s += v;
    sq += v * v;
  }
  __shared__ float ls[4][2][64];
  ls[rs][0][h] = s;
  ls[rs][1][h] = sq;
  __syncthreads();
  if (threadIdx.x < 64) {
    float ts = ls[0][0][h] + ls[1][0][h] + ls[2][0][h] + ls[3][0][h];
    float tq = ls[0][1][h] + ls[1][1][h] + ls[2][1][h] + ls[3][1][h];
    atomicAdd(&stats[h], ts);
    atomicAdd(&stats[64 + h], tq);
  }
}

// -------------------- x = softplus(BN(o_mean) + x) --------------------
__global__ __launch_bounds__(256) void k_update(float* __restrict__ x,
                                                const float* __restrict__ o,
                                                const float* __restrict__ stats,
                                                const float* __restrict__ g,
                                                const float* __restrict__ b) {
  int t = blockIdx.x * 256 + threadIdx.x;  // N*64
  int h = t & 63;
  float mean = stats[h] * (1.f / N_NODES);
  float var = stats[64 + h] * (1.f / N_NODES) - mean * mean;
  float is = rsqrtf(var + EPSB);
  float v = (o[t] - mean) * is * g[h] + b[h];
  x[t] = sp_f(v + x[t]);
}

// ------- graph pooling: chunked register accumulation (batch is sorted) -------
#define PR 512
__global__ __launch_bounds__(256) void k_pool(const float* __restrict__ x,
                                              const int* __restrict__ batch,
                                              float* __restrict__ pooled,
                                              float* __restrict__ gcnt) {
  int h = threadIdx.x & 63, rs = threadIdx.x >> 6;
  int r0 = blockIdx.x * PR;
  int rend = min(r0 + PR, N_NODES);
  int gcur = -1;
  float acc = 0.f;
  int cnt = 0;
  for (int r = r0 + rs; r < rend; r += 4) {
    int g = batch[r];
    if (g != gcur) {
      if (gcur >= 0) {
        atomicAdd(&pooled[gcur * 64 + h], acc);
        if (h == 0) atomicAdd(&gcnt[gcur], (float)cnt);
      }
      gcur = g;
      acc = 0.f;
      cnt = 0;
    }
    acc += x[r * 64 + h];
    cnt++;
  }
  if (gcur >= 0) {
    atomicAdd(&pooled[gcur * 64 + h], acc);
    if (h == 0) atomicAdd(&gcnt[gcur], (float)cnt);
  }
}

// -------------------- final dense layers --------------------
__global__ __launch_bounds__(128) void k_final(const float* __restrict__ pooled,
                                               const float* __restrict__ gcnt,
                                               const float* __restrict__ l2w,
                                               const float* __restrict__ l2b,
                                               const float* __restrict__ ow,
                                               const float* __restrict__ ob,
                                               float* __restrict__ out) {
  int g = blockIdx.x;
  int t = threadIdx.x;
  __shared__ float row[64];
  __shared__ float hh[128];
  if (t < 64) row[t] = pooled[g * 64 + t] / fmaxf(gcnt[g], 1.f);
  __syncthreads();
  float acc = l2b[t];
  for (int k = 0; k < 64; ++k) acc += row[k] * l2w[k * 128 + t];
  hh[t] = sp_f(acc) * ow[t];
  __syncthreads();
  for (int s = 64; s > 0; s >>= 1) {
    if (t < s) hh[t] += hh[t + s];
    __syncthreads();
  }
  if (t == 0) out[g] = hh[0] + ob[0];
}

extern "C" void kernel_launch(void* const* d_in, const int* in_sizes, int n_in,
                              void* d_out, int out_size, void* d_ws, size_t ws_size,
                              hipStream_t stream) {
  const float* x_in = (const float*)d_in[0];
  const int* node_idx = (const int*)d_in[1];
  const int* hedge_idx = (const int*)d_in[2];
  const float* hedge_attr = (const float*)d_in[3];
  const int* batch = (const int*)d_in[4];
  const float* embed_w = (const float*)d_in[5];
  const float* embed_b = (const float*)d_in[6];
  const float* f1_w = (const float*)d_in[7];
  const float* c1_w = (const float*)d_in[9];
  const float* f2_w = (const float*)d_in[11];
  const float* f2_b = (const float*)d_in[12];
  const float* c2_w = (const float*)d_in[13];
  const float* c2_b = (const float*)d_in[14];
  const float* bnf_g = (const float*)d_in[15];
  const float* bnf_b = (const float*)d_in[16];
  const float* bnc_g = (const float*)d_in[17];
  const float* bnc_b = (const float*)d_in[18];
  const float* bno_g = (const float*)d_in[19];
  const float* bno_b = (const float*)d_in[20];
  const float* l2_w = (const float*)d_in[21];
  const float* l2_b = (const float*)d_in[22];
  const float* out_w = (const float*)d_in[23];
  const float* out_b = (const float*)d_in[24];

  // workspace layout (bytes, 256-aligned)
  char* base = (char*)d_ws;
  size_t off = 0;
  auto alloc = [&](size_t bytes) {
    size_t o = off;
    off = (off + bytes + 255) & ~(size_t)255;
    return o;
  };
  float* xbuf = (float*)(base + alloc((size_t)N_NODES * 64 * 4));
  float* hxVf = (float*)(base + alloc((size_t)N_HEDGES * 64 * 4));  // hx, later Vf
  float* Vc = (float*)(base + alloc((size_t)N_HEDGES * 64 * 4));
  float* ha0 = (float*)(base + alloc((size_t)N_HEDGES * 35 * 4));
  // contiguous region Uf|Uc|obuf (76.8 MB) also aliases Z (200K x 72 = 57.6 MB):
  // Z live only between k_hedge_gemm and k_hedge_apply; Uf/Uc/obuf written after.
  float* Uf = (float*)(base + alloc((size_t)N_NODES * 64 * 4));
  float* Uc = (float*)(base + alloc((size_t)N_NODES * 64 * 4));
  float* obuf = (float*)(base + alloc((size_t)N_NODES * 64 * 4));
  float* zbuf = Uf;
  float* hstats = (float*)(base + alloc(144 * 4));
  float* ostats = (float*)(base + alloc(128 * 4));
  float* pooled = (float*)(base + alloc((size_t)N_GRAPHS * 64 * 4));
  float* gcnt = (float*)(base + alloc((size_t)N_GRAPHS * 4));
  int* degH = (int*)(base + alloc((size_t)N_HEDGES * 4));
  int* offH = (int*)(base + alloc((size_t)N_HEDGES * 4));
  int* curH = (int*)(base + alloc((size_t)N_HEDGES * 4));
  int* degN = (int*)(base + alloc((size_t)N_NODES * 4));
  int* offN = (int*)(base + alloc((size_t)N_NODES * 4));
  int* curN = (int*)(base + alloc((size_t)N_NODES * 4));
  int* permHn = (int*)(base + alloc((size_t)N_INC * 4));
  int* permNh = (int*)(base + alloc((size_t)N_INC * 4));
  int* gctr = (int*)(base + alloc(2 * 4));
  (void)ws_size;
  (void)in_sizes;
  (void)n_in;
  (void)out_size;

  // ---- CSR build (index lists are call-invariant) ----
  hipMemsetAsync(degH, 0, (size_t)N_HEDGES * 4, stream);
  hipMemsetAsync(degN, 0, (size_t)N_NODES * 4, stream);
  hipMemsetAsync(gctr, 0, 2 * 4, stream);
  k_hist<<<(N_INC + 255) / 256, 256, 0, stream>>>(node_idx, hedge_idx, degN, degH);
  k_alloc<<<(N_HEDGES + 255) / 256, 256, 0, stream>>>(degH, N_HEDGES, offH, curH, &gctr[0]);
  k_alloc<<<(N_NODES + 255) / 256, 256, 0, stream>>>(degN, N_NODES, offN, curN, &gctr[1]);
  k_fill<<<(N_INC + 255) / 256, 256, 0, stream>>>(node_idx, hedge_idx, curH, curN,
                                                  permHn, permNh);

  // embed
  k_embed<<<N_NODES / 16, 256, 0, stream>>>(x_in, embed_w, embed_b, xbuf);

  for (int i = 0; i < 3; ++i) {
    const float* ha_in = (i == 0) ? hedge_attr : ha0;
    float* ha_out = ha0;

    // hedge aggregation (CSR gather, mean folded in)
    k_gather_hx<<<N_HEDGES * 64 / 256, 256, 0, stream>>>(xbuf, permHn, offH, degH, hxVf);

    // hedge GEMM (single pass, stats from registers) + BN/activation apply
    hipMemsetAsync(hstats, 0, 144 * 4, stream);
    k_hedge_gemm<<<(N_HEDGES + HROWS - 1) / HROWS, 256, 0, stream>>>(
        hxVf, ha_in, f1_w + i * CAT * HE, c1_w + i * CAT * HE, zbuf, hstats);
    k_hedge_apply<<<(N_HEDGES * 35 + 255) / 256, 256, 0, stream>>>(
        zbuf, hstats, bnf_g + i * HE, bnf_b + i * HE, bnc_g + i * HE, bnc_b + i * HE,
        ha_out);

    // node/hedge projections (linearity split of the per-incidence matmul)
    k_uv_node<<<N_NODES / 16, 256, 0, stream>>>(xbuf, f2_w + i * CAT * 64,
                                                c2_w + i * CAT * 64, Uf, Uc);
    k_uv_hedge<<<N_HEDGES / 16, 256, 0, stream>>>(
        ha_out, f2_w + i * CAT * 64 + 64 * 64, c2_w + i * CAT * 64 + 64 * 64,
        f2_b + i * 64, c2_b + i * 64, hxVf /*Vf*/, Vc);

    // per-node combine via CSR (no atomics, mean folded in)
    k_node_aggr<<<N_NODES * 64 / 256, 256, 0, stream>>>(permNh, offN, degN, Uf, Uc,
                                                        hxVf /*Vf*/, Vc, obuf);

    // node BN + residual softplus
    hipMemsetAsync(ostats, 0, 128 * 4, stream);
    k_ostats<<<1024, 256, 0, stream>>>(obuf, ostats);
    k_update<<<N_NODES * 64 / 256, 256, 0, stream>>>(xbuf, obuf, ostats,
                                                     bno_g + i * 64, bno_b + i * 64);
  }

  // pooling + head
  hipMemsetAsync(pooled, 0, (size_t)N_GRAPHS * 64 * 4, stream);
  hipMemsetAsync(gcnt, 0, (size_t)N_GRAPHS * 4, stream);
  k_pool<<<(N_NODES + PR - 1) / PR, 256, 0, stream>>>(xbuf, batch, pooled, gcnt);
  k_final<<<N_GRAPHS, 128, 0, stream>>>(pooled, gcnt, l2_w, l2_b, out_w, out_b,
                                        (float*)d_out);
}

// Round 4
// 1726.654 us; speedup vs baseline: 2.3652x; 1.4290x over previous
//
#include <hip/hip_runtime.h>
#include <math.h>

#define N_NODES 100000
#define N_HEDGES 200000
#define N_INC 1000000
#define N_GRAPHS 256
#define HD 64
#define HE 35
#define CAT 99
#define EPSB 1e-5f

__device__ __forceinline__ float sp_f(float x) {
  // softplus = max(x,0) + log1p(exp(-|x|)), fast native exp/log
  return fmaxf(x, 0.f) + __logf(1.f + __expf(-fabsf(x)));
}
__device__ __forceinline__ float sig_f(float x) {
  return __builtin_amdgcn_rcpf(1.f + __expf(-x));
}
// bf16 helpers: RNE pack, trivial unpack
__device__ __forceinline__ unsigned bfr(float x) {
  unsigned u = __float_as_uint(x);
  return (u + 0x7fffu + ((u >> 16) & 1u)) >> 16;
}
__device__ __forceinline__ unsigned pk2(float lo, float hi) {
  return bfr(lo) | (bfr(hi) << 16);
}
__device__ __forceinline__ float blo(unsigned v) {
  return __uint_as_float(v << 16);
}
__device__ __forceinline__ float bhi(unsigned v) {
  return __uint_as_float(v & 0xffff0000u);
}
__device__ __forceinline__ float bf2f(unsigned short s) {
  return __uint_as_float(((unsigned)s) << 16);
}

// -------------------- int degree histogram --------------------
__global__ __launch_bounds__(256) void k_hist(const int* __restrict__ nidx,
                                              const int* __restrict__ hidx,
                                              int* __restrict__ degN,
                                              int* __restrict__ degH) {
  int e = blockIdx.x * 256 + threadIdx.x;
  if (e >= N_INC) return;
  atomicAdd(&degH[hidx[e]], 1);
  atomicAdd(&degN[nidx[e]], 1);
}

// ---- CSR offsets: block inclusive scan + one global atomic base per block ----
__global__ __launch_bounds__(256) void k_alloc(const int* __restrict__ deg, int n,
                                               int* __restrict__ off,
                                               int* __restrict__ cur,
                                               int* __restrict__ gctr) {
  __shared__ int s[256];
  __shared__ int base;
  int t = threadIdx.x;
  int i = blockIdx.x * 256 + t;
  int d = (i < n) ? deg[i] : 0;
  s[t] = d;
  __syncthreads();
  for (int st = 1; st < 256; st <<= 1) {
    int u = 0;
    if (t >= st) u = s[t - st];
    __syncthreads();
    if (t >= st) s[t] += u;
    __syncthreads();
  }
  if (t == 255) base = atomicAdd(gctr, s[255]);
  __syncthreads();
  int ex = s[t] - d + base;
  if (i < n) {
    off[i] = ex;
    cur[i] = ex;
  }
}

__global__ __launch_bounds__(256) void k_fill(const int* __restrict__ nidx,
                                              const int* __restrict__ hidx,
                                              int* __restrict__ curH,
                                              int* __restrict__ curN,
                                              int* __restrict__ permHn,
                                              int* __restrict__ permNh) {
  int e = blockIdx.x * 256 + threadIdx.x;
  if (e >= N_INC) return;
  int nd = nidx[e], hg = hidx[e];
  int p = atomicAdd(&curH[hg], 1);
  permHn[p] = nd;
  int q = atomicAdd(&curN[nd], 1);
  permNh[q] = hg;
}

// -------------------- embed: x[N,92] @ w[92,64] + b (writes f32 + bf16) -----------
__global__ __launch_bounds__(256) void k_embed(const float* __restrict__ x,
                                               const float* __restrict__ w,
                                               const float* __restrict__ b,
                                               float* __restrict__ out,
                                               unsigned short* __restrict__ outb) {
  __shared__ float ws[92 * 64];
  __shared__ float rs[16][93];
  int tid = threadIdx.x;
  for (int i = tid; i < 92 * 64; i += 256) ws[i] = w[i];
  int r0 = blockIdx.x * 16;
  for (int i = tid; i < 16 * 92; i += 256) {
    int r = i / 92, k = i - r * 92;
    rs[r][k] = x[(r0 + r) * 92 + k];
  }
  __syncthreads();
  int h = tid & 63;
  float bias = b[h];
  for (int rr = tid >> 6; rr < 16; rr += 4) {
    float acc = bias;
    for (int k = 0; k < 92; ++k) acc += rs[rr][k] * ws[k * 64 + h];
    out[(r0 + rr) * 64 + h] = acc;
    outb[(r0 + rr) * 64 + h] = (unsigned short)bfr(acc);
  }
}

// --------- hedge gather-mean via CSR (bf16 x, unrolled x4) ---------
__global__ __launch_bounds__(256) void k_gather_hx(
    const unsigned short* __restrict__ xb, const int* __restrict__ permHn,
    const int* __restrict__ offH, const int* __restrict__ degH,
    float* __restrict__ hx) {
  int gt = blockIdx.x * 256 + threadIdx.x;
  int wid = gt >> 6, h = gt & 63;
  if (wid >= N_HEDGES) return;
  int o = offH[wid], d = degH[wid];
  float acc = 0.f;
  int k = 0;
  for (; k + 4 <= d; k += 4) {
    int n0 = permHn[o + k], n1 = permHn[o + k + 1];
    int n2 = permHn[o + k + 2], n3 = permHn[o + k + 3];
    float a0 = bf2f(xb[n0 * 64 + h]);
    float a1 = bf2f(xb[n1 * 64 + h]);
    float a2 = bf2f(xb[n2 * 64 + h]);
    float a3 = bf2f(xb[n3 * 64 + h]);
    acc += (a0 + a1) + (a2 + a3);
  }
  for (; k < d; ++k) acc += bf2f(xb[permHn[o + k] * 64 + h]);
  hx[wid * 64 + h] = acc / (float)max(d, 1);
}

// ------ hedge GEMM, single pass: Z[r][72] = msg[r][99] @ [Wf|Wc], + col stats ------
#define HROWS 112
#define HSTR 100  // padded k-stride (25 float4)
__global__ __launch_bounds__(256) void k_hedge_gemm(
    const float* __restrict__ hx, const float* __restrict__ ha_in,
    const float* __restrict__ w_f, const float* __restrict__ w_c,
    float* __restrict__ z, float* __restrict__ stats) {
  __shared__ float wfT[36 * HSTR];
  __shared__ float wcT[36 * HSTR];
  __shared__ float msg[HROWS * HSTR];
  __shared__ float ps[144];
  int tid = threadIdx.x;
  for (int i = tid; i < 36 * HSTR; i += 256) {
    int c = i / HSTR, k = i - c * HSTR;
    float vf = 0.f, vc = 0.f;
    if (c < 35 && k < 99) {
      vf = w_f[k * 35 + c];
      vc = w_c[k * 35 + c];
    }
    wfT[i] = vf;
    wcT[i] = vc;
  }
  if (tid < 144) ps[tid] = 0.f;
  int r0 = blockIdx.x * HROWS;
  for (int i = tid; i < HROWS * HSTR; i += 256) {
    int r = i / HSTR, k = i - r * HSTR;
    int row = r0 + r;
    float v = 0.f;
    if (row < N_HEDGES) {
      if (k < 64)
        v = hx[row * 64 + k];
      else if (k < 99)
        v = ha_in[row * 35 + (k - 64)];
    }
    msg[i] = v;
  }
  __syncthreads();
  if (tid < 252) {
    int s = tid % 18, rg = tid / 18;
    float accf0[8], accf1[8], accc0[8], accc1[8];
#pragma unroll
    for (int j = 0; j < 8; ++j) accf0[j] = accf1[j] = accc0[j] = accc1[j] = 0.f;
    const float4* wf0p = (const float4*)&wfT[s * HSTR];
    const float4* wf1p = (const float4*)&wfT[(s + 18) * HSTR];
    const float4* wc0p = (const float4*)&wcT[s * HSTR];
    const float4* wc1p = (const float4*)&wcT[(s + 18) * HSTR];
    for (int kk = 0; kk < 25; ++kk) {
      float4 wf0 = wf0p[kk], wf1 = wf1p[kk], wc0 = wc0p[kk], wc1 = wc1p[kk];
#pragma unroll
      for (int j = 0; j < 8; ++j) {
        float4 m = ((const float4*)&msg[(rg * 8 + j) * HSTR])[kk];
        accf0[j] += m.x * wf0.x + m.y * wf0.y + m.z * wf0.z + m.w * wf0.w;
        accf1[j] += m.x * wf1.x + m.y * wf1.y + m.z * wf1.z + m.w * wf1.w;
        accc0[j] += m.x * wc0.x + m.y * wc0.y + m.z * wc0.z + m.w * wc0.w;
        accc1[j] += m.x * wc1.x + m.y * wc1.y + m.z * wc1.z + m.w * wc1.w;
      }
    }
    float sf0 = 0, qf0 = 0, sf1 = 0, qf1 = 0, sc0 = 0, qc0 = 0, sc1 = 0, qc1 = 0;
#pragma unroll
    for (int j = 0; j < 8; ++j) {
      int row = r0 + rg * 8 + j;
      if (row < N_HEDGES) {
        float zf0 = accf0[j], zf1 = accf1[j], zc0 = accc0[j], zc1 = accc1[j];
        float* zr = &z[(size_t)row * 72];
        zr[s] = zf0;
        zr[s + 18] = zf1;
        zr[36 + s] = zc0;
        zr[54 + s] = zc1;
        sf0 += zf0; qf0 += zf0 * zf0;
        sf1 += zf1; qf1 += zf1 * zf1;
        sc0 += zc0; qc0 += zc0 * zc0;
        sc1 += zc1; qc1 += zc1 * zc1;
      }
    }
    atomicAdd(&ps[s], sf0);
    atomicAdd(&ps[s + 18], sf1);
    atomicAdd(&ps[36 + s], qf0);
    atomicAdd(&ps[54 + s], qf1);
    atomicAdd(&ps[72 + s], sc0);
    atomicAdd(&ps[90 + s], sc1);
    atomicAdd(&ps[108 + s], qc0);
    atomicAdd(&ps[126 + s], qc1);
  }
  __syncthreads();
  if (tid < 144) atomicAdd(&stats[tid], ps[tid]);
}

// ---- elementwise BN + sigmoid*softplus over Z -> ha_out[200K][35] ----
__global__ __launch_bounds__(256) void k_hedge_apply(
    const float* __restrict__ z, const float* __restrict__ stats,
    const float* __restrict__ gf, const float* __restrict__ bf_,
    const float* __restrict__ gc, const float* __restrict__ bc_,
    float* __restrict__ ha_out) {
  int t = blockIdx.x * 256 + threadIdx.x;
  if (t >= N_HEDGES * 35) return;
  int r = t / 35, c = t - r * 35;
  float mf = stats[c] * (1.f / N_HEDGES);
  float vf = stats[36 + c] * (1.f / N_HEDGES) - mf * mf;
  float mc = stats[72 + c] * (1.f / N_HEDGES);
  float vc = stats[108 + c] * (1.f / N_HEDGES) - mc * mc;
  const float* zr = &z[(size_t)r * 72];
  float nf = (zr[c] - mf) * rsqrtf(vf + EPSB) * gf[c] + bf_[c];
  float nc = (zr[36 + c] - mc) * rsqrtf(vc + EPSB) * gc[c] + bc_[c];
  ha_out[t] = sig_f(nf) * sp_f(nc);
}

// ---- per-node projection: U = x @ W[0:64,:], packed bf16x2 (f,c) output ----
__global__ __launch_bounds__(256) void k_uv_node(const float* __restrict__ x,
                                                 const float* __restrict__ f2w,
                                                 const float* __restrict__ c2w,
                                                 unsigned* __restrict__ Ufc) {
  __shared__ float wf[64 * 64];
  __shared__ float wc[64 * 64];
  __shared__ float rs[16][65];
  int tid = threadIdx.x;
  for (int i = tid; i < 64 * 64; i += 256) {
    wf[i] = f2w[i];
    wc[i] = c2w[i];
  }
  int r0 = blockIdx.x * 16;
  for (int i = tid; i < 16 * 64; i += 256) {
    int r = i >> 6, k = i & 63;
    rs[r][k] = x[(r0 + r) * 64 + k];
  }
  __syncthreads();
  int h = tid & 63, rb = tid >> 6;
  float af0 = 0, af1 = 0, af2 = 0, af3 = 0, ac0 = 0, ac1 = 0, ac2 = 0, ac3 = 0;
  for (int k = 0; k < 64; ++k) {
    float wfv = wf[k * 64 + h], wcv = wc[k * 64 + h];
    float m0 = rs[rb][k], m1 = rs[rb + 4][k], m2 = rs[rb + 8][k], m3 = rs[rb + 12][k];
    af0 += m0 * wfv; ac0 += m0 * wcv;
    af1 += m1 * wfv; ac1 += m1 * wcv;
    af2 += m2 * wfv; ac2 += m2 * wcv;
    af3 += m3 * wfv; ac3 += m3 * wcv;
  }
  int row = r0 + rb;
  Ufc[row * 64 + h] = pk2(af0, ac0);
  Ufc[(row + 4) * 64 + h] = pk2(af1, ac1);
  Ufc[(row + 8) * 64 + h] = pk2(af2, ac2);
  Ufc[(row + 12) * 64 + h] = pk2(af3, ac3);
}

// ---- per-hedge projection: V = ha @ W[64:99,:] + bias, packed bf16x2 output ----
__global__ __launch_bounds__(256) void k_uv_hedge(const float* __restrict__ ha,
                                                  const float* __restrict__ f2wb,
                                                  const float* __restrict__ c2wb,
                                                  const float* __restrict__ f2b,
                                                  const float* __restrict__ c2b,
                                                  unsigned* __restrict__ Vfc) {
  __shared__ float wf[35 * 64];
  __shared__ float wc[35 * 64];
  __shared__ float rs[16][36];
  int tid = threadIdx.x;
  for (int i = tid; i < 35 * 64; i += 256) {
    wf[i] = f2wb[i];
    wc[i] = c2wb[i];
  }
  int r0 = blockIdx.x * 16;
  for (int i = tid; i < 16 * 35; i += 256) {
    int r = i / 35, k = i - r * 35;
    rs[r][k] = ha[(r0 + r) * 35 + k];
  }
  __syncthreads();
  int h = tid & 63, rb = tid >> 6;
  float af0, af1, af2, af3, ac0, ac1, ac2, ac3;
  af0 = af1 = af2 = af3 = f2b[h];
  ac0 = ac1 = ac2 = ac3 = c2b[h];
  for (int k = 0; k < 35; ++k) {
    float wfv = wf[k * 64 + h], wcv = wc[k * 64 + h];
    float m0 = rs[rb][k], m1 = rs[rb + 4][k], m2 = rs[rb + 8][k], m3 = rs[rb + 12][k];
    af0 += m0 * wfv; ac0 += m0 * wcv;
    af1 += m1 * wfv; ac1 += m1 * wcv;
    af2 += m2 * wfv; ac2 += m2 * wcv;
    af3 += m3 * wfv; ac3 += m3 * wcv;
  }
  int row = r0 + rb;
  Vfc[row * 64 + h] = pk2(af0, ac0);
  Vfc[(row + 4) * 64 + h] = pk2(af1, ac1);
  Vfc[(row + 8) * 64 + h] = pk2(af2, ac2);
  Vfc[(row + 12) * 64 + h] = pk2(af3, ac3);
}

// ------ per-node aggregate via CSR: packed bf16 U/V, unrolled x4, fast act ------
__device__ __forceinline__ float act2(float uf, float uc, unsigned v) {
  float a = uf + blo(v);
  float b = uc + bhi(v);
  return sig_f(a) * sp_f(b);
}
__global__ __launch_bounds__(256) void k_node_aggr(const int* __restrict__ permNh,
                                                   const int* __restrict__ offN,
                                                   const int* __restrict__ degN,
                                                   const unsigned* __restrict__ Ufc,
                                                   const unsigned* __restrict__ Vfc,
                                                   float* __restrict__ o) {
  int gt = blockIdx.x * 256 + threadIdx.x;
  int wid = gt >> 6, h = gt & 63;
  if (wid >= N_NODES) return;
  int off = offN[wid], d = degN[wid];
  unsigned u = Ufc[wid * 64 + h];
  float uf = blo(u), uc = bhi(u);
  float acc = 0.f;
  int k = 0;
  for (; k + 4 <= d; k += 4) {
    int h0 = permNh[off + k], h1 = permNh[off + k + 1];
    int h2 = permNh[off + k + 2], h3 = permNh[off + k + 3];
    unsigned v0 = Vfc[h0 * 64 + h];
    unsigned v1 = Vfc[h1 * 64 + h];
    unsigned v2 = Vfc[h2 * 64 + h];
    unsigned v3 = Vfc[h3 * 64 + h];
    acc += (act2(uf, uc, v0) + act2(uf, uc, v1)) +
           (act2(uf, uc, v2) + act2(uf, uc, v3));
  }
  for (; k < d; ++k) acc += act2(uf, uc, Vfc[permNh[off + k] * 64 + h]);
  o[wid * 64 + h] = acc / (float)max(d, 1);
}

// -------------------- BN stats over node features --------------------
__global__ __launch_bounds__(256) void k_ostats(const float* __restrict__ o,
                                                float* __restrict__ stats) {
  int h = threadIdx.x & 63;
  int rs = threadIdx.x >> 6;
  float s = 0.f, sq = 0.f;
  for (int r = blockIdx.x * 4 + rs; r < N_NODES; r += gridDim.x * 4) {
    float v = o[r * 64 + h];
    s += v;
    sq += v * v;
  }
  __shared__ float ls[4][2][64];
  ls[rs][0][h] = s;
  ls[rs][1][h] = sq;
  __syncthreads();
  if (threadIdx.x < 64) {
    float ts = ls[0][0][h] + ls[1][0][h] + ls[2][0][h] + ls[3][0][h];
    float tq = ls[0][1][h] + ls[1][1][h] + ls[2][1][h] + ls[3][1][h];
    atomicAdd(&stats[h], ts);
    atomicAdd(&stats[64 + h], tq);
  }
}

// ---------- x = softplus(BN(o_mean) + x), writes f32 + bf16 copies ----------
__global__ __launch_bounds__(256) void k_update(float* __restrict__ x,
                                                unsigned short* __restrict__ xb,
                                                const float* __restrict__ o,
                                                const float* __restrict__ stats,
                                                const float* __restrict__ g,
                                                const float* __restrict__ b) {
  int t = blockIdx.x * 256 + threadIdx.x;  // N*64
  int h = t & 63;
  float mean = stats[h] * (1.f / N_NODES);
  float var = stats[64 + h] * (1.f / N_NODES) - mean * mean;
  float is = rsqrtf(var + EPSB);
  float v = (o[t] - mean) * is * g[h] + b[h];
  float r = sp_f(v + x[t]);
  x[t] = r;
  xb[t] = (unsigned short)bfr(r);
}

// ------- graph pooling: chunked register accumulation (batch is sorted) -------
#define PR 512
__global__ __launch_bounds__(256) void k_pool(const float* __restrict__ x,
                                              const int* __restrict__ batch,
                                              float* __restrict__ pooled,
                                              float* __restrict__ gcnt) {
  int h = threadIdx.x & 63, rs = threadIdx.x >> 6;
  int r0 = blockIdx.x * PR;
  int rend = min(r0 + PR, N_NODES);
  int gcur = -1;
  float acc = 0.f;
  int cnt = 0;
  for (int r = r0 + rs; r < rend; r += 4) {
    int g = batch[r];
    if (g != gcur) {
      if (gcur >= 0) {
        atomicAdd(&pooled[gcur * 64 + h], acc);
        if (h == 0) atomicAdd(&gcnt[gcur], (float)cnt);
      }
      gcur = g;
      acc = 0.f;
      cnt = 0;
    }
    acc += x[r * 64 + h];
    cnt++;
  }
  if (gcur >= 0) {
    atomicAdd(&pooled[gcur * 64 + h], acc);
    if (h == 0) atomicAdd(&gcnt[gcur], (float)cnt);
  }
}

// -------------------- final dense layers --------------------
__global__ __launch_bounds__(128) void k_final(const float* __restrict__ pooled,
                                               const float* __restrict__ gcnt,
                                               const float* __restrict__ l2w,
                                               const float* __restrict__ l2b,
                                               const float* __restrict__ ow,
                                               const float* __restrict__ ob,
                                               float* __restrict__ out) {
  int g = blockIdx.x;
  int t = threadIdx.x;
  __shared__ float row[64];
  __shared__ float hh[128];
  if (t < 64) row[t] = pooled[g * 64 + t] / fmaxf(gcnt[g], 1.f);
  __syncthreads();
  float acc = l2b[t];
  for (int k = 0; k < 64; ++k) acc += row[k] * l2w[k * 128 + t];
  hh[t] = sp_f(acc) * ow[t];
  __syncthreads();
  for (int s = 64; s > 0; s >>= 1) {
    if (t < s) hh[t] += hh[t + s];
    __syncthreads();
  }
  if (t == 0) out[g] = hh[0] + ob[0];
}

extern "C" void kernel_launch(void* const* d_in, const int* in_sizes, int n_in,
                              void* d_out, int out_size, void* d_ws, size_t ws_size,
                              hipStream_t stream) {
  const float* x_in = (const float*)d_in[0];
  const int* node_idx = (const int*)d_in[1];
  const int* hedge_idx = (const int*)d_in[2];
  const float* hedge_attr = (const float*)d_in[3];
  const int* batch = (const int*)d_in[4];
  const float* embed_w = (const float*)d_in[5];
  const float* embed_b = (const float*)d_in[6];
  const float* f1_w = (const float*)d_in[7];
  const float* c1_w = (const float*)d_in[9];
  const float* f2_w = (const float*)d_in[11];
  const float* f2_b = (const float*)d_in[12];
  const float* c2_w = (const float*)d_in[13];
  const float* c2_b = (const float*)d_in[14];
  const float* bnf_g = (const float*)d_in[15];
  const float* bnf_b = (const float*)d_in[16];
  const float* bnc_g = (const float*)d_in[17];
  const float* bnc_b = (const float*)d_in[18];
  const float* bno_g = (const float*)d_in[19];
  const float* bno_b = (const float*)d_in[20];
  const float* l2_w = (const float*)d_in[21];
  const float* l2_b = (const float*)d_in[22];
  const float* out_w = (const float*)d_in[23];
  const float* out_b = (const float*)d_in[24];

  // workspace layout (bytes, 256-aligned)
  char* base = (char*)d_ws;
  size_t off = 0;
  auto alloc = [&](size_t bytes) {
    size_t o = off;
    off = (off + bytes + 255) & ~(size_t)255;
    return o;
  };
  float* xbuf = (float*)(base + alloc((size_t)N_NODES * 64 * 4));
  unsigned short* xbf = (unsigned short*)(base + alloc((size_t)N_NODES * 64 * 2));
  // hx (f32, live until k_hedge_gemm) aliases Vfc (uint, written by k_uv_hedge after)
  float* hx = (float*)(base + alloc((size_t)N_HEDGES * 64 * 4));
  unsigned* Vfc = (unsigned*)hx;
  float* ha0 = (float*)(base + alloc((size_t)N_HEDGES * 35 * 4));
  float* zbuf = (float*)(base + alloc((size_t)N_HEDGES * 72 * 4));
  unsigned* Ufc = (unsigned*)(base + alloc((size_t)N_NODES * 64 * 4));
  float* obuf = (float*)(base + alloc((size_t)N_NODES * 64 * 4));
  float* hstats = (float*)(base + alloc(144 * 4));
  float* ostats = (float*)(base + alloc(128 * 4));
  float* pooled = (float*)(base + alloc((size_t)N_GRAPHS * 64 * 4));
  float* gcnt = (float*)(base + alloc((size_t)N_GRAPHS * 4));
  int* degH = (int*)(base + alloc((size_t)N_HEDGES * 4));
  int* offH = (int*)(base + alloc((size_t)N_HEDGES * 4));
  int* curH = (int*)(base + alloc((size_t)N_HEDGES * 4));
  int* degN = (int*)(base + alloc((size_t)N_NODES * 4));
  int* offN = (int*)(base + alloc((size_t)N_NODES * 4));
  int* curN = (int*)(base + alloc((size_t)N_NODES * 4));
  int* permHn = (int*)(base + alloc((size_t)N_INC * 4));
  int* permNh = (int*)(base + alloc((size_t)N_INC * 4));
  int* gctr = (int*)(base + alloc(2 * 4));
  (void)ws_size;
  (void)in_sizes;
  (void)n_in;
  (void)out_size;

  // ---- CSR build (index lists are call-invariant) ----
  hipMemsetAsync(degH, 0, (size_t)N_HEDGES * 4, stream);
  hipMemsetAsync(degN, 0, (size_t)N_NODES * 4, stream);
  hipMemsetAsync(gctr, 0, 2 * 4, stream);
  k_hist<<<(N_INC + 255) / 256, 256, 0, stream>>>(node_idx, hedge_idx, degN, degH);
  k_alloc<<<(N_HEDGES + 255) / 256, 256, 0, stream>>>(degH, N_HEDGES, offH, curH, &gctr[0]);
  k_alloc<<<(N_NODES + 255) / 256, 256, 0, stream>>>(degN, N_NODES, offN, curN, &gctr[1]);
  k_fill<<<(N_INC + 255) / 256, 256, 0, stream>>>(node_idx, hedge_idx, curH, curN,
                                                  permHn, permNh);

  // embed
  k_embed<<<N_NODES / 16, 256, 0, stream>>>(x_in, embed_w, embed_b, xbuf, xbf);

  for (int i = 0; i < 3; ++i) {
    const float* ha_in = (i == 0) ? hedge_attr : ha0;
    float* ha_out = ha0;

    // hedge aggregation (CSR gather from bf16 x, mean folded in)
    k_gather_hx<<<N_HEDGES * 64 / 256, 256, 0, stream>>>(xbf, permHn, offH, degH, hx);

    // hedge GEMM (single pass, stats from registers) + BN/activation apply
    hipMemsetAsync(hstats, 0, 144 * 4, stream);
    k_hedge_gemm<<<(N_HEDGES + HROWS - 1) / HROWS, 256, 0, stream>>>(
        hx, ha_in, f1_w + i * CAT * HE, c1_w + i * CAT * HE, zbuf, hstats);
    k_hedge_apply<<<(N_HEDGES * 35 + 255) / 256, 256, 0, stream>>>(
        zbuf, hstats, bnf_g + i * HE, bnf_b + i * HE, bnc_g + i * HE, bnc_b + i * HE,
        ha_out);

    // node/hedge projections (linearity split), packed bf16x2 outputs
    k_uv_node<<<N_NODES / 16, 256, 0, stream>>>(xbuf, f2_w + i * CAT * 64,
                                                c2_w + i * CAT * 64, Ufc);
    k_uv_hedge<<<N_HEDGES / 16, 256, 0, stream>>>(
        ha_out, f2_w + i * CAT * 64 + 64 * 64, c2_w + i * CAT * 64 + 64 * 64,
        f2_b + i * 64, c2_b + i * 64, Vfc);

    // per-node combine via CSR (no atomics, mean folded in)
    k_node_aggr<<<N_NODES * 64 / 256, 256, 0, stream>>>(permNh, offN, degN, Ufc, Vfc,
                                                        obuf);

    // node BN + residual softplus
    hipMemsetAsync(ostats, 0, 128 * 4, stream);
    k_ostats<<<1024, 256, 0, stream>>>(obuf, ostats);
    k_update<<<N_NODES * 64 / 256, 256, 0, stream>>>(xbuf, xbf, obuf, ostats,
                                                     bno_g + i * 64, bno_b + i * 64);
  }

  // pooling + head
  hipMemsetAsync(pooled, 0, (size_t)N_GRAPHS * 64 * 4, stream);
  hipMemsetAsync(gcnt, 0, (size_t)N_GRAPHS * 4, stream);
  k_pool<<<(N_NODES + PR - 1) / PR, 256, 0, stream>>>(xbuf, batch, pooled, gcnt);
  k_final<<<N_GRAPHS, 128, 0, stream>>>(pooled, gcnt, l2_w, l2_b, out_w, out_b,
                                        (float*)d_out);
}

// Round 5
// 1460.193 us; speedup vs baseline: 2.7968x; 1.1825x over previous
//
#include <hip/hip_runtime.h>
#include <math.h>

#define N_NODES 100000
#define N_HEDGES 200000
#define N_INC 1000000
#define N_GRAPHS 256
#define HD 64
#define HE 35
#define CAT 99
#define EPSB 1e-5f

typedef __attribute__((ext_vector_type(8))) short short8;
typedef __attribute__((ext_vector_type(4))) float f32x4;

__device__ __forceinline__ float sp_f(float x) {
  return fmaxf(x, 0.f) + __logf(1.f + __expf(-fabsf(x)));
}
__device__ __forceinline__ float sig_f(float x) {
  return __builtin_amdgcn_rcpf(1.f + __expf(-x));
}
__device__ __forceinline__ unsigned bfr(float x) {
  unsigned u = __float_as_uint(x);
  return (u + 0x7fffu + ((u >> 16) & 1u)) >> 16;
}
__device__ __forceinline__ unsigned pk2(float lo, float hi) {
  return bfr(lo) | (bfr(hi) << 16);
}
__device__ __forceinline__ float blo(unsigned v) { return __uint_as_float(v << 16); }
__device__ __forceinline__ float bhi(unsigned v) {
  return __uint_as_float(v & 0xffff0000u);
}
__device__ __forceinline__ float bf2f(unsigned short s) {
  return __uint_as_float(((unsigned)s) << 16);
}

// -------------------- int degree histogram --------------------
__global__ __launch_bounds__(256) void k_hist(const int* __restrict__ nidx,
                                              const int* __restrict__ hidx,
                                              int* __restrict__ degN,
                                              int* __restrict__ degH) {
  int e = blockIdx.x * 256 + threadIdx.x;
  if (e >= N_INC) return;
  atomicAdd(&degH[hidx[e]], 1);
  atomicAdd(&degN[nidx[e]], 1);
}

// ---- CSR offsets: block inclusive scan + one global atomic base per block ----
__global__ __launch_bounds__(256) void k_alloc(const int* __restrict__ deg, int n,
                                               int* __restrict__ off,
                                               int* __restrict__ cur,
                                               int* __restrict__ gctr) {
  __shared__ int s[256];
  __shared__ int base;
  int t = threadIdx.x;
  int i = blockIdx.x * 256 + t;
  int d = (i < n) ? deg[i] : 0;
  s[t] = d;
  __syncthreads();
  for (int st = 1; st < 256; st <<= 1) {
    int u = 0;
    if (t >= st) u = s[t - st];
    __syncthreads();
    if (t >= st) s[t] += u;
    __syncthreads();
  }
  if (t == 255) base = atomicAdd(gctr, s[255]);
  __syncthreads();
  int ex = s[t] - d + base;
  if (i < n) {
    off[i] = ex;
    cur[i] = ex;
  }
}

__global__ __launch_bounds__(256) void k_fill(const int* __restrict__ nidx,
                                              const int* __restrict__ hidx,
                                              int* __restrict__ curH,
                                              int* __restrict__ curN,
                                              int* __restrict__ permHn,
                                              int* __restrict__ permNh) {
  int e = blockIdx.x * 256 + threadIdx.x;
  if (e >= N_INC) return;
  int nd = nidx[e], hg = hidx[e];
  int p = atomicAdd(&curH[hg], 1);
  permHn[p] = nd;
  int q = atomicAdd(&curN[nd], 1);
  permNh[q] = hg;
}

// ---- weight prepack: B[k=0..127][col=0..79] = [Wf | Wc | pad] as MFMA B-frags ----
// wpk[layer][ct(5)][ks(4)][lane(64)] = uint4 of 8 bf16: B[ks*32+(l>>4)*8+j][ct*16+(l&15)]
__global__ __launch_bounds__(64) void k_wpack(const float* __restrict__ f1w,
                                              const float* __restrict__ c1w,
                                              uint4* __restrict__ wpk) {
  int b = blockIdx.x;  // 60 = 3 layers * 5 ct * 4 ks
  int layer = b / 20, rem = b % 20, ct = rem / 4, ks = rem % 4;
  int lane = threadIdx.x;
  int col = ct * 16 + (lane & 15);
  int k0 = ks * 32 + (lane >> 4) * 8;
  const float* wf = f1w + layer * CAT * HE;
  const float* wc = c1w + layer * CAT * HE;
  unsigned v[4];
#pragma unroll
  for (int p = 0; p < 4; ++p) {
    float lo = 0.f, hi = 0.f;
    int ka = k0 + p * 2, kb = ka + 1;
    if (ka < 99) {
      if (col < 35) lo = wf[ka * 35 + col];
      else if (col >= 36 && col < 71) lo = wc[ka * 35 + (col - 36)];
    }
    if (kb < 99) {
      if (col < 35) hi = wf[kb * 35 + col];
      else if (col >= 36 && col < 71) hi = wc[kb * 35 + (col - 36)];
    }
    v[p] = pk2(lo, hi);
  }
  uint4 o;
  o.x = v[0]; o.y = v[1]; o.z = v[2]; o.w = v[3];
  wpk[b * 64 + lane] = o;
}

// ---- hedge_attr f32 -> bf16 once ----
__global__ __launch_bounds__(256) void k_cvt_ha(const float* __restrict__ src,
                                                unsigned short* __restrict__ dst,
                                                int n) {
  int t = blockIdx.x * 256 + threadIdx.x;
  if (t < n) dst[t] = (unsigned short)bfr(src[t]);
}

// -------------------- embed: x[N,92] @ w[92,64] + b (writes f32 + bf16) -----------
__global__ __launch_bounds__(256) void k_embed(const float* __restrict__ x,
                                               const float* __restrict__ w,
                                               const float* __restrict__ b,
                                               float* __restrict__ out,
                                               unsigned short* __restrict__ outb) {
  __shared__ float ws[92 * 64];
  __shared__ float rs[16][93];
  int tid = threadIdx.x;
  for (int i = tid; i < 92 * 64; i += 256) ws[i] = w[i];
  int r0 = blockIdx.x * 16;
  for (int i = tid; i < 16 * 92; i += 256) {
    int r = i / 92, k = i - r * 92;
    rs[r][k] = x[(r0 + r) * 92 + k];
  }
  __syncthreads();
  int h = tid & 63;
  float bias = b[h];
  for (int rr = tid >> 6; rr < 16; rr += 4) {
    float acc = bias;
    for (int k = 0; k < 92; ++k) acc += rs[rr][k] * ws[k * 64 + h];
    out[(r0 + rr) * 64 + h] = acc;
    outb[(r0 + rr) * 64 + h] = (unsigned short)bfr(acc);
  }
}

// --------- hedge gather-mean via CSR (bf16 in, bf16 out, unrolled x4) ---------
__global__ __launch_bounds__(256) void k_gather_hx(
    const unsigned short* __restrict__ xb, const int* __restrict__ permHn,
    const int* __restrict__ offH, const int* __restrict__ degH,
    unsigned short* __restrict__ hxb) {
  int gt = blockIdx.x * 256 + threadIdx.x;
  int wid = gt >> 6, h = gt & 63;
  if (wid >= N_HEDGES) return;
  int o = offH[wid], d = degH[wid];
  float acc = 0.f;
  int k = 0;
  for (; k + 4 <= d; k += 4) {
    int n0 = permHn[o + k], n1 = permHn[o + k + 1];
    int n2 = permHn[o + k + 2], n3 = permHn[o + k + 3];
    float a0 = bf2f(xb[n0 * 64 + h]);
    float a1 = bf2f(xb[n1 * 64 + h]);
    float a2 = bf2f(xb[n2 * 64 + h]);
    float a3 = bf2f(xb[n3 * 64 + h]);
    acc += (a0 + a1) + (a2 + a3);
  }
  for (; k < d; ++k) acc += bf2f(xb[permHn[o + k] * 64 + h]);
  hxb[wid * 64 + h] = (unsigned short)bfr(acc / (float)max(d, 1));
}

// ------ hedge GEMM via MFMA: Z[200K][72] = msg[200K][99] @ B[99][72], + col stats ------
// block: 256 thr (4 waves), 128 rows; wave w owns rows w*32..w*32+31 (2 16-row tiles).
// msg LDS [128][128] bf16, XOR-swizzled (byte ^= (row&7)<<4) for conflict-free b128.
#define GR 128
__global__ __launch_bounds__(256) void k_hedge_gemm(
    const unsigned short* __restrict__ hxb, const unsigned short* __restrict__ hab,
    const uint4* __restrict__ wpk, float* __restrict__ z,
    float* __restrict__ stats) {
  __shared__ unsigned short msg[GR * 128];
  __shared__ float ps[160];
  int tid = threadIdx.x;
  int w = tid >> 6, lane = tid & 63;
  int r0 = blockIdx.x * GR;
  if (tid < 160) ps[tid] = 0.f;

  // B-fragments straight to registers (L2-resident after first touch)
  short8 bfg[5][4];
#pragma unroll
  for (int ct = 0; ct < 5; ++ct)
#pragma unroll
    for (int ks = 0; ks < 4; ++ks)
      bfg[ct][ks] = __builtin_bit_cast(short8, wpk[(ct * 4 + ks) * 64 + lane]);

  char* mb = (char*)msg;
  // stage cols 0-63 from hxb (ushort4 chunks)
  for (int i = tid; i < GR * 16; i += 256) {
    int r = i >> 4, c4 = (i & 15) * 4;
    int row = r0 + r;
    ushort4 v;
    if (row < N_HEDGES)
      v = *(const ushort4*)(hxb + (size_t)row * 64 + c4);
    else
      v.x = v.y = v.z = v.w = 0;
    int byte = r * 256 + c4 * 2;
    *(ushort4*)(mb + (byte ^ ((r & 7) << 4))) = v;
  }
  // stage cols 64-98 from hab, 99-127 zero (scalar)
  for (int i = tid; i < GR * 64; i += 256) {
    int r = i >> 6, c = 64 + (i & 63);
    int row = r0 + r;
    unsigned short v = 0;
    if (row < N_HEDGES && c < 99) v = hab[(size_t)row * 35 + (c - 64)];
    int byte = r * 256 + c * 2;
    *(unsigned short*)(mb + (byte ^ ((r & 7) << 4))) = v;
  }
  __syncthreads();

#pragma unroll
  for (int rt = 0; rt < 2; ++rt) {
    int rloc = w * 32 + rt * 16 + (lane & 15);
    short8 a[4];
#pragma unroll
    for (int ks = 0; ks < 4; ++ks) {
      int byte = rloc * 256 + (ks * 32 + (lane >> 4) * 8) * 2;
      a[ks] = *(const short8*)(mb + (byte ^ ((rloc & 7) << 4)));
    }
#pragma unroll
    for (int ct = 0; ct < 5; ++ct) {
      f32x4 acc = {0.f, 0.f, 0.f, 0.f};
#pragma unroll
      for (int ks = 0; ks < 4; ++ks)
        acc = __builtin_amdgcn_mfma_f32_16x16x32_bf16(a[ks], bfg[ct][ks], acc, 0, 0, 0);
      // column stats (OOB rows contribute 0 since msg zero-filled)
      float s = (acc[0] + acc[1]) + (acc[2] + acc[3]);
      float q = (acc[0] * acc[0] + acc[1] * acc[1]) +
                (acc[2] * acc[2] + acc[3] * acc[3]);
      s += __shfl_xor(s, 16);
      s += __shfl_xor(s, 32);
      q += __shfl_xor(q, 16);
      q += __shfl_xor(q, 32);
      int col = ct * 16 + (lane & 15);
      if ((lane >> 4) == 0 && col < 72) {
        atomicAdd(&ps[col], s);
        atomicAdd(&ps[80 + col], q);
      }
      int growb = r0 + w * 32 + rt * 16 + ((lane >> 4) << 2);
      if (col < 72) {
#pragma unroll
        for (int r = 0; r < 4; ++r) {
          int grow = growb + r;
          if (grow < N_HEDGES) z[(size_t)grow * 72 + col] = acc[r];
        }
      }
    }
  }
  __syncthreads();
  if (tid < 160) atomicAdd(&stats[tid], ps[tid]);
}

// ---- elementwise BN + sigmoid*softplus over Z -> ha (bf16) ----
// Z cols: 0-34 = zf, 36-70 = zc. stats: sum[80] at [0..79], sumsq at [80..159].
__global__ __launch_bounds__(256) void k_hedge_apply(
    const float* __restrict__ z, const float* __restrict__ stats,
    const float* __restrict__ gf, const float* __restrict__ bf_,
    const float* __restrict__ gc, const float* __restrict__ bc_,
    unsigned short* __restrict__ hab) {
  int t = blockIdx.x * 256 + threadIdx.x;
  if (t >= N_HEDGES * 35) return;
  int r = t / 35, c = t - r * 35;
  const float inv = 1.f / N_HEDGES;
  float mf = stats[c] * inv;
  float vf = stats[80 + c] * inv - mf * mf;
  float mc = stats[36 + c] * inv;
  float vc = stats[116 + c] * inv - mc * mc;
  const float* zr = &z[(size_t)r * 72];
  float nf = (zr[c] - mf) * rsqrtf(vf + EPSB) * gf[c] + bf_[c];
  float nc = (zr[36 + c] - mc) * rsqrtf(vc + EPSB) * gc[c] + bc_[c];
  hab[t] = (unsigned short)bfr(sig_f(nf) * sp_f(nc));
}

// ---- per-node projection: U = x @ W[0:64,:], packed bf16x2 (f,c) output ----
__global__ __launch_bounds__(256) void k_uv_node(const float* __restrict__ x,
                                                 const float* __restrict__ f2w,
                                                 const float* __restrict__ c2w,
                                                 unsigned* __restrict__ Ufc) {
  __shared__ float wf[64 * 64];
  __shared__ float wc[64 * 64];
  __shared__ float rs[16][65];
  int tid = threadIdx.x;
  for (int i = tid; i < 64 * 64; i += 256) {
    wf[i] = f2w[i];
    wc[i] = c2w[i];
  }
  int r0 = blockIdx.x * 16;
  for (int i = tid; i < 16 * 64; i += 256) {
    int r = i >> 6, k = i & 63;
    rs[r][k] = x[(r0 + r) * 64 + k];
  }
  __syncthreads();
  int h = tid & 63, rb = tid >> 6;
  float af0 = 0, af1 = 0, af2 = 0, af3 = 0, ac0 = 0, ac1 = 0, ac2 = 0, ac3 = 0;
  for (int k = 0; k < 64; ++k) {
    float wfv = wf[k * 64 + h], wcv = wc[k * 64 + h];
    float m0 = rs[rb][k], m1 = rs[rb + 4][k], m2 = rs[rb + 8][k], m3 = rs[rb + 12][k];
    af0 += m0 * wfv; ac0 += m0 * wcv;
    af1 += m1 * wfv; ac1 += m1 * wcv;
    af2 += m2 * wfv; ac2 += m2 * wcv;
    af3 += m3 * wfv; ac3 += m3 * wcv;
  }
  int row = r0 + rb;
  Ufc[row * 64 + h] = pk2(af0, ac0);
  Ufc[(row + 4) * 64 + h] = pk2(af1, ac1);
  Ufc[(row + 8) * 64 + h] = pk2(af2, ac2);
  Ufc[(row + 12) * 64 + h] = pk2(af3, ac3);
}

// ---- per-hedge projection: V = ha @ W[64:99,:] + bias, bf16 in, packed bf16 out ----
__global__ __launch_bounds__(256) void k_uv_hedge(
    const unsigned short* __restrict__ hab, const float* __restrict__ f2wb,
    const float* __restrict__ c2wb, const float* __restrict__ f2b,
    const float* __restrict__ c2b, unsigned* __restrict__ Vfc) {
  __shared__ float wf[35 * 64];
  __shared__ float wc[35 * 64];
  __shared__ float rs[16][36];
  int tid = threadIdx.x;
  for (int i = tid; i < 35 * 64; i += 256) {
    wf[i] = f2wb[i];
    wc[i] = c2wb[i];
  }
  int r0 = blockIdx.x * 16;
  for (int i = tid; i < 16 * 35; i += 256) {
    int r = i / 35, k = i - r * 35;
    rs[r][k] = bf2f(hab[(r0 + r) * 35 + k]);
  }
  __syncthreads();
  int h = tid & 63, rb = tid >> 6;
  float af0, af1, af2, af3, ac0, ac1, ac2, ac3;
  af0 = af1 = af2 = af3 = f2b[h];
  ac0 = ac1 = ac2 = ac3 = c2b[h];
  for (int k = 0; k < 35; ++k) {
    float wfv = wf[k * 64 + h], wcv = wc[k * 64 + h];
    float m0 = rs[rb][k], m1 = rs[rb + 4][k], m2 = rs[rb + 8][k], m3 = rs[rb + 12][k];
    af0 += m0 * wfv; ac0 += m0 * wcv;
    af1 += m1 * wfv; ac1 += m1 * wcv;
    af2 += m2 * wfv; ac2 += m2 * wcv;
    af3 += m3 * wfv; ac3 += m3 * wcv;
  }
  int row = r0 + rb;
  Vfc[row * 64 + h] = pk2(af0, ac0);
  Vfc[(row + 4) * 64 + h] = pk2(af1, ac1);
  Vfc[(row + 8) * 64 + h] = pk2(af2, ac2);
  Vfc[(row + 12) * 64 + h] = pk2(af3, ac3);
}

// ------ per-node aggregate via CSR: packed bf16 U/V, unrolled x4, fast act ------
__device__ __forceinline__ float act2(float uf, float uc, unsigned v) {
  float a = uf + blo(v);
  float b = uc + bhi(v);
  return sig_f(a) * sp_f(b);
}
__global__ __launch_bounds__(256) void k_node_aggr(const int* __restrict__ permNh,
                                                   const int* __restrict__ offN,
                                                   const int* __restrict__ degN,
                                                   const unsigned* __restrict__ Ufc,
                                                   const unsigned* __restrict__ Vfc,
                                                   float* __restrict__ o) {
  int gt = blockIdx.x * 256 + threadIdx.x;
  int wid = gt >> 6, h = gt & 63;
  if (wid >= N_NODES) return;
  int off = offN[wid], d = degN[wid];
  unsigned u = Ufc[wid * 64 + h];
  float uf = blo(u), uc = bhi(u);
  float acc = 0.f;
  int k = 0;
  for (; k + 4 <= d; k += 4) {
    int h0 = permNh[off + k], h1 = permNh[off + k + 1];
    int h2 = permNh[off + k + 2], h3 = permNh[off + k + 3];
    unsigned v0 = Vfc[h0 * 64 + h];
    unsigned v1 = Vfc[h1 * 64 + h];
    unsigned v2 = Vfc[h2 * 64 + h];
    unsigned v3 = Vfc[h3 * 64 + h];
    acc += (act2(uf, uc, v0) + act2(uf, uc, v1)) +
           (act2(uf, uc, v2) + act2(uf, uc, v3));
  }
  for (; k < d; ++k) acc += act2(uf, uc, Vfc[permNh[off + k] * 64 + h]);
  o[wid * 64 + h] = acc / (float)max(d, 1);
}

// -------------------- BN stats over node features --------------------
__global__ __launch_bounds__(256) void k_ostats(const float* __restrict__ o,
                                                float* __restrict__ stats) {
  int h = threadIdx.x & 63;
  int rs = threadIdx.x >> 6;
  float s = 0.f, sq = 0.f;
  for (int r = blockIdx.x * 4 + rs; r < N_NODES; r += gridDim.x * 4) {
    float v = o[r * 64 + h];
    s += v;
    sq += v * v;
  }
  __shared__ float ls[4][2][64];
  ls[rs][0][h] = s;
  ls[rs][1][h] = sq;
  __syncthreads();
  if (threadIdx.x < 64) {
    float ts = ls[0][0][h] + ls[1][0][h] + ls[2][0][h] + ls[3][0][h];
    float tq = ls[0][1][h] + ls[1][1][h] + ls[2][1][h] + ls[3][1][h];
    atomicAdd(&stats[h], ts);
    atomicAdd(&stats[64 + h], tq);
  }
}

// ---------- x = softplus(BN(o_mean) + x), writes f32 + bf16 copies ----------
__global__ __launch_bounds__(256) void k_update(float* __restrict__ x,
                                                unsigned short* __restrict__ xb,
                                                const float* __restrict__ o,
                                                const float* __restrict__ stats,
                                                const float* __restrict__ g,
                                                const float* __restrict__ b) {
  int t = blockIdx.x * 256 + threadIdx.x;
  int h = t & 63;
  float mean = stats[h] * (1.f / N_NODES);
  float var = stats[64 + h] * (1.f / N_NODES) - mean * mean;
  float is = rsqrtf(var + EPSB);
  float v = (o[t] - mean) * is * g[h] + b[h];
  float r = sp_f(v + x[t]);
  x[t] = r;
  xb[t] = (unsigned short)bfr(r);
}

// ------- graph pooling: chunked register accumulation (batch is sorted) -------
#define PR 512
__global__ __launch_bounds__(256) void k_pool(const float* __restrict__ x,
                                              const int* __restrict__ batch,
                                              float* __restrict__ pooled,
                                              float* __restrict__ gcnt) {
  int h = threadIdx.x & 63, rs = threadIdx.x >> 6;
  int r0 = blockIdx.x * PR;
  int rend = min(r0 + PR, N_NODES);
  int gcur = -1;
  float acc = 0.f;
  int cnt = 0;
  for (int r = r0 + rs; r < rend; r += 4) {
    int g = batch[r];
    if (g != gcur) {
      if (gcur >= 0) {
        atomicAdd(&pooled[gcur * 64 + h], acc);
        if (h == 0) atomicAdd(&gcnt[gcur], (float)cnt);
      }
      gcur = g;
      acc = 0.f;
      cnt = 0;
    }
    acc += x[r * 64 + h];
    cnt++;
  }
  if (gcur >= 0) {
    atomicAdd(&pooled[gcur * 64 + h], acc);
    if (h == 0) atomicAdd(&gcnt[gcur], (float)cnt);
  }
}

// -------------------- final dense layers --------------------
__global__ __launch_bounds__(128) void k_final(const float* __restrict__ pooled,
                                               const float* __restrict__ gcnt,
                                               const float* __restrict__ l2w,
                                               const float* __restrict__ l2b,
                                               const float* __restrict__ ow,
                                               const float* __restrict__ ob,
                                               float* __restrict__ out) {
  int g = blockIdx.x;
  int t = threadIdx.x;
  __shared__ float row[64];
  __shared__ float hh[128];
  if (t < 64) row[t] = pooled[g * 64 + t] / fmaxf(gcnt[g], 1.f);
  __syncthreads();
  float acc = l2b[t];
  for (int k = 0; k < 64; ++k) acc += row[k] * l2w[k * 128 + t];
  hh[t] = sp_f(acc) * ow[t];
  __syncthreads();
  for (int s = 64; s > 0; s >>= 1) {
    if (t < s) hh[t] += hh[t + s];
    __syncthreads();
  }
  if (t == 0) out[g] = hh[0] + ob[0];
}

extern "C" void kernel_launch(void* const* d_in, const int* in_sizes, int n_in,
                              void* d_out, int out_size, void* d_ws, size_t ws_size,
                              hipStream_t stream) {
  const float* x_in = (const float*)d_in[0];
  const int* node_idx = (const int*)d_in[1];
  const int* hedge_idx = (const int*)d_in[2];
  const float* hedge_attr = (const float*)d_in[3];
  const int* batch = (const int*)d_in[4];
  const float* embed_w = (const float*)d_in[5];
  const float* embed_b = (const float*)d_in[6];
  const float* f1_w = (const float*)d_in[7];
  const float* c1_w = (const float*)d_in[9];
  const float* f2_w = (const float*)d_in[11];
  const float* f2_b = (const float*)d_in[12];
  const float* c2_w = (const float*)d_in[13];
  const float* c2_b = (const float*)d_in[14];
  const float* bnf_g = (const float*)d_in[15];
  const float* bnf_b = (const float*)d_in[16];
  const float* bnc_g = (const float*)d_in[17];
  const float* bnc_b = (const float*)d_in[18];
  const float* bno_g = (const float*)d_in[19];
  const float* bno_b = (const float*)d_in[20];
  const float* l2_w = (const float*)d_in[21];
  const float* l2_b = (const float*)d_in[22];
  const float* out_w = (const float*)d_in[23];
  const float* out_b = (const float*)d_in[24];

  // workspace layout (bytes, 256-aligned)
  char* base = (char*)d_ws;
  size_t off = 0;
  auto alloc = [&](size_t bytes) {
    size_t o = off;
    off = (off + bytes + 255) & ~(size_t)255;
    return o;
  };
  float* xbuf = (float*)(base + alloc((size_t)N_NODES * 64 * 4));
  unsigned short* xbf = (unsigned short*)(base + alloc((size_t)N_NODES * 64 * 2));
  unsigned short* hxb = (unsigned short*)(base + alloc((size_t)N_HEDGES * 64 * 2));
  unsigned short* hab = (unsigned short*)(base + alloc((size_t)N_HEDGES * 35 * 2));
  // region R: Vfc (51.2MB) + obuf (25.6MB); zbuf (57.6MB) aliases R —
  // zbuf live gemm->apply only; Vfc (uv_hedge) and obuf (node_aggr) written after.
  unsigned* Vfc = (unsigned*)(base + alloc((size_t)N_HEDGES * 64 * 4));
  float* obuf = (float*)(base + alloc((size_t)N_NODES * 64 * 4));
  float* zbuf = (float*)Vfc;
  unsigned* Ufc = (unsigned*)(base + alloc((size_t)N_NODES * 64 * 4));
  uint4* wpk = (uint4*)(base + alloc((size_t)60 * 64 * 16));
  float* hstats = (float*)(base + alloc(160 * 4));
  float* ostats = (float*)(base + alloc(128 * 4));
  float* pooled = (float*)(base + alloc((size_t)N_GRAPHS * 64 * 4));
  float* gcnt = (float*)(base + alloc((size_t)N_GRAPHS * 4));
  int* degH = (int*)(base + alloc((size_t)N_HEDGES * 4));
  int* offH = (int*)(base + alloc((size_t)N_HEDGES * 4));
  int* curH = (int*)(base + alloc((size_t)N_HEDGES * 4));
  int* degN = (int*)(base + alloc((size_t)N_NODES * 4));
  int* offN = (int*)(base + alloc((size_t)N_NODES * 4));
  int* curN = (int*)(base + alloc((size_t)N_NODES * 4));
  int* permHn = (int*)(base + alloc((size_t)N_INC * 4));
  int* permNh = (int*)(base + alloc((size_t)N_INC * 4));
  int* gctr = (int*)(base + alloc(2 * 4));
  (void)ws_size;
  (void)in_sizes;
  (void)n_in;
  (void)out_size;

  // ---- CSR build + weight prepack + ha conversion ----
  hipMemsetAsync(degH, 0, (size_t)N_HEDGES * 4, stream);
  hipMemsetAsync(degN, 0, (size_t)N_NODES * 4, stream);
  hipMemsetAsync(gctr, 0, 2 * 4, stream);
  k_hist<<<(N_INC + 255) / 256, 256, 0, stream>>>(node_idx, hedge_idx, degN, degH);
  k_alloc<<<(N_HEDGES + 255) / 256, 256, 0, stream>>>(degH, N_HEDGES, offH, curH, &gctr[0]);
  k_alloc<<<(N_NODES + 255) / 256, 256, 0, stream>>>(degN, N_NODES, offN, curN, &gctr[1]);
  k_fill<<<(N_INC + 255) / 256, 256, 0, stream>>>(node_idx, hedge_idx, curH, curN,
                                                  permHn, permNh);
  k_wpack<<<60, 64, 0, stream>>>(f1_w, c1_w, wpk);
  k_cvt_ha<<<(N_HEDGES * 35 + 255) / 256, 256, 0, stream>>>(hedge_attr, hab,
                                                            N_HEDGES * 35);

  // embed
  k_embed<<<N_NODES / 16, 256, 0, stream>>>(x_in, embed_w, embed_b, xbuf, xbf);

  for (int i = 0; i < 3; ++i) {
    // hedge aggregation (CSR gather from bf16 x, mean folded in, bf16 out)
    k_gather_hx<<<N_HEDGES * 64 / 256, 256, 0, stream>>>(xbf, permHn, offH, degH, hxb);

    // hedge GEMM (MFMA, single pass, stats from C-frags) + BN/activation apply
    hipMemsetAsync(hstats, 0, 160 * 4, stream);
    k_hedge_gemm<<<(N_HEDGES + GR - 1) / GR, 256, 0, stream>>>(
        hxb, hab, wpk + (size_t)i * 20 * 64, zbuf, hstats);
    k_hedge_apply<<<(N_HEDGES * 35 + 255) / 256, 256, 0, stream>>>(
        zbuf, hstats, bnf_g + i * HE, bnf_b + i * HE, bnc_g + i * HE, bnc_b + i * HE,
        hab);

    // node/hedge projections (linearity split), packed bf16x2 outputs
    k_uv_node<<<N_NODES / 16, 256, 0, stream>>>(xbuf, f2_w + i * CAT * 64,
                                                c2_w + i * CAT * 64, Ufc);
    k_uv_hedge<<<N_HEDGES / 16, 256, 0, stream>>>(
        hab, f2_w + i * CAT * 64 + 64 * 64, c2_w + i * CAT * 64 + 64 * 64,
        f2_b + i * 64, c2_b + i * 64, Vfc);

    // per-node combine via CSR (no atomics, mean folded in)
    k_node_aggr<<<N_NODES * 64 / 256, 256, 0, stream>>>(permNh, offN, degN, Ufc, Vfc,
                                                        obuf);

    // node BN + residual softplus
    hipMemsetAsync(ostats, 0, 128 * 4, stream);
    k_ostats<<<1024, 256, 0, stream>>>(obuf, ostats);
    k_update<<<N_NODES * 64 / 256, 256, 0, stream>>>(xbuf, xbf, obuf, ostats,
                                                     bno_g + i * 64, bno_b + i * 64);
  }

  // pooling + head
  hipMemsetAsync(pooled, 0, (size_t)N_GRAPHS * 64 * 4, stream);
  hipMemsetAsync(gcnt, 0, (size_t)N_GRAPHS * 4, stream);
  k_pool<<<(N_NODES + PR - 1) / PR, 256, 0, stream>>>(xbuf, batch, pooled, gcnt);
  k_final<<<N_GRAPHS, 128, 0, stream>>>(pooled, gcnt, l2_w, l2_b, out_w, out_b,
                                        (float*)d_out);
}

// Round 6
// 1386.113 us; speedup vs baseline: 2.9463x; 1.0534x over previous
//
#include <hip/hip_runtime.h>
#include <math.h>

#define N_NODES 100000
#define N_HEDGES 200000
#define N_INC 1000000
#define N_GRAPHS 256
#define HD 64
#define HE 35
#define CAT 99
#define EPSB 1e-5f

typedef __attribute__((ext_vector_type(8))) short short8;
typedef __attribute__((ext_vector_type(4))) float f32x4;

__device__ __forceinline__ float sp_f(float x) {
  return fmaxf(x, 0.f) + __logf(1.f + __expf(-fabsf(x)));
}
__device__ __forceinline__ float sig_f(float x) {
  return __builtin_amdgcn_rcpf(1.f + __expf(-x));
}
__device__ __forceinline__ unsigned bfr(float x) {
  unsigned u = __float_as_uint(x);
  return (u + 0x7fffu + ((u >> 16) & 1u)) >> 16;
}
__device__ __forceinline__ unsigned pk2(float lo, float hi) {
  return bfr(lo) | (bfr(hi) << 16);
}
__device__ __forceinline__ float blo(unsigned v) { return __uint_as_float(v << 16); }
__device__ __forceinline__ float bhi(unsigned v) {
  return __uint_as_float(v & 0xffff0000u);
}
__device__ __forceinline__ float bf2f(unsigned short s) {
  return __uint_as_float(((unsigned)s) << 16);
}

// ---- histogram + within-segment ranks (atomic return captured, coalesced write) ----
__global__ __launch_bounds__(256) void k_hist(const int* __restrict__ nidx,
                                              const int* __restrict__ hidx,
                                              int* __restrict__ degN,
                                              int* __restrict__ degH,
                                              int* __restrict__ rankN,
                                              int* __restrict__ rankH) {
  int e = blockIdx.x * 256 + threadIdx.x;
  if (e >= N_INC) return;
  rankH[e] = atomicAdd(&degH[hidx[e]], 1);
  rankN[e] = atomicAdd(&degN[nidx[e]], 1);
}

// ---- CSR offsets for BOTH segmentations in one launch ----
#define CHB ((N_HEDGES + 255) / 256)
#define CNB ((N_NODES + 255) / 256)
__global__ __launch_bounds__(256) void k_alloc2(const int* __restrict__ degH,
                                                const int* __restrict__ degN,
                                                int* __restrict__ offH,
                                                int* __restrict__ offN,
                                                int* __restrict__ gctr) {
  __shared__ int s[256];
  __shared__ int base;
  int b = blockIdx.x, t = threadIdx.x;
  const int* deg;
  int* off;
  int n, i;
  int* ctr;
  if (b < CHB) {
    deg = degH; off = offH; n = N_HEDGES; ctr = &gctr[0]; i = b * 256 + t;
  } else {
    deg = degN; off = offN; n = N_NODES; ctr = &gctr[1]; i = (b - CHB) * 256 + t;
  }
  int d = (i < n) ? deg[i] : 0;
  s[t] = d;
  __syncthreads();
  for (int st = 1; st < 256; st <<= 1) {
    int u = 0;
    if (t >= st) u = s[t - st];
    __syncthreads();
    if (t >= st) s[t] += u;
    __syncthreads();
  }
  if (t == 255) base = atomicAdd(ctr, s[255]);
  __syncthreads();
  if (i < n) off[i] = s[t] - d + base;
}

// ---- atomic-free CSR fill: position = off[seg] + precomputed rank ----
__global__ __launch_bounds__(256) void k_fill(const int* __restrict__ nidx,
                                              const int* __restrict__ hidx,
                                              const int* __restrict__ rankH,
                                              const int* __restrict__ rankN,
                                              const int* __restrict__ offH,
                                              const int* __restrict__ offN,
                                              int* __restrict__ permHn,
                                              int* __restrict__ permNh) {
  int e = blockIdx.x * 256 + threadIdx.x;
  if (e >= N_INC) return;
  int nd = nidx[e], hg = hidx[e];
  permHn[offH[hg] + rankH[e]] = nd;
  permNh[offN[nd] + rankN[e]] = hg;
}

// ---- weight prepack: B[k=0..127][col=0..79] = [Wf | Wc | pad] as MFMA B-frags ----
__global__ __launch_bounds__(64) void k_wpack(const float* __restrict__ f1w,
                                              const float* __restrict__ c1w,
                                              uint4* __restrict__ wpk) {
  int b = blockIdx.x;  // 60 = 3 layers * 5 ct * 4 ks
  int layer = b / 20, rem = b % 20, ct = rem / 4, ks = rem % 4;
  int lane = threadIdx.x;
  int col = ct * 16 + (lane & 15);
  int k0 = ks * 32 + (lane >> 4) * 8;
  const float* wf = f1w + layer * CAT * HE;
  const float* wc = c1w + layer * CAT * HE;
  unsigned v[4];
#pragma unroll
  for (int p = 0; p < 4; ++p) {
    float lo = 0.f, hi = 0.f;
    int ka = k0 + p * 2, kb = ka + 1;
    if (ka < 99) {
      if (col < 35) lo = wf[ka * 35 + col];
      else if (col >= 36 && col < 71) lo = wc[ka * 35 + (col - 36)];
    }
    if (kb < 99) {
      if (col < 35) hi = wf[kb * 35 + col];
      else if (col >= 36 && col < 71) hi = wc[kb * 35 + (col - 36)];
    }
    v[p] = pk2(lo, hi);
  }
  uint4 o;
  o.x = v[0]; o.y = v[1]; o.z = v[2]; o.w = v[3];
  wpk[b * 64 + lane] = o;
}

// ---- hedge_attr f32 -> bf16 once ----
__global__ __launch_bounds__(256) void k_cvt_ha(const float* __restrict__ src,
                                                unsigned short* __restrict__ dst,
                                                int n) {
  int t = blockIdx.x * 256 + threadIdx.x;
  if (t < n) dst[t] = (unsigned short)bfr(src[t]);
}

// -------------------- embed: x[N,92] @ w[92,64] + b -> bf16 --------------------
__global__ __launch_bounds__(256) void k_embed(const float* __restrict__ x,
                                               const float* __restrict__ w,
                                               const float* __restrict__ b,
                                               unsigned short* __restrict__ outb) {
  __shared__ float ws[92 * 64];
  __shared__ float rs[16][93];
  int tid = threadIdx.x;
  for (int i = tid; i < 92 * 64; i += 256) ws[i] = w[i];
  int r0 = blockIdx.x * 16;
  for (int i = tid; i < 16 * 92; i += 256) {
    int r = i / 92, k = i - r * 92;
    rs[r][k] = x[(r0 + r) * 92 + k];
  }
  __syncthreads();
  int h = tid & 63;
  float bias = b[h];
  for (int rr = tid >> 6; rr < 16; rr += 4) {
    float acc = bias;
    for (int k = 0; k < 92; ++k) acc += rs[rr][k] * ws[k * 64 + h];
    outb[(r0 + rr) * 64 + h] = (unsigned short)bfr(acc);
  }
}

// ------ FUSED hedge gather-mean + MFMA GEMM + col stats ------
// block: 256 thr (4 waves), 128 rows; wave w gathers AND computes rows w*32..w*32+31
// (wave-private LDS region -> no barrier between gather and A-frag reads).
// msg LDS [128][128] bf16, XOR-swizzled (byte ^= (row&7)<<4).
#define GR 128
__global__ __launch_bounds__(256) void k_hedge_gemm(
    const unsigned short* __restrict__ xb, const int* __restrict__ permHn,
    const int* __restrict__ offH, const int* __restrict__ degH,
    const unsigned short* __restrict__ hab, const uint4* __restrict__ wpk,
    float* __restrict__ z, float* __restrict__ stats) {
  __shared__ unsigned short msg[GR * 128];
  __shared__ float ps[160];
  int tid = threadIdx.x;
  int w = tid >> 6, lane = tid & 63;
  int r0 = blockIdx.x * GR;
  if (tid < 160) ps[tid] = 0.f;

  // B-fragments straight to registers (L2-resident)
  short8 bfg[5][4];
#pragma unroll
  for (int ct = 0; ct < 5; ++ct)
#pragma unroll
    for (int ks = 0; ks < 4; ++ks)
      bfg[ct][ks] = __builtin_bit_cast(short8, wpk[(ct * 4 + ks) * 64 + lane]);

  char* mb = (char*)msg;
  // wave-private gather: CSR mean of member-node rows + ha columns
  for (int r = 0; r < 32; ++r) {
    int rloc = w * 32 + r;
    int row = r0 + rloc;
    float acc = 0.f;
    unsigned short hv = 0;
    if (row < N_HEDGES) {
      int o = offH[row], d = degH[row];  // wave-uniform -> scalar loads
      int k = 0;
      for (; k + 4 <= d; k += 4) {
        int n0 = permHn[o + k], n1 = permHn[o + k + 1];
        int n2 = permHn[o + k + 2], n3 = permHn[o + k + 3];
        acc += (bf2f(xb[(size_t)n0 * 64 + lane]) + bf2f(xb[(size_t)n1 * 64 + lane])) +
               (bf2f(xb[(size_t)n2 * 64 + lane]) + bf2f(xb[(size_t)n3 * 64 + lane]));
      }
      for (; k < d; ++k) acc += bf2f(xb[(size_t)permHn[o + k] * 64 + lane]);
      acc *= 1.f / (float)max(d, 1);
      if (lane < 35) hv = hab[(size_t)row * 35 + lane];
    }
    int swz = (rloc & 7) << 4;
    *(unsigned short*)(mb + ((rloc * 256 + lane * 2) ^ swz)) = (unsigned short)bfr(acc);
    *(unsigned short*)(mb + ((rloc * 256 + 128 + lane * 2) ^ swz)) = hv;
  }
  __syncthreads();  // ps-init visibility (msg is wave-private)

#pragma unroll
  for (int rt = 0; rt < 2; ++rt) {
    int rloc = w * 32 + rt * 16 + (lane & 15);
    short8 a[4];
#pragma unroll
    for (int ks = 0; ks < 4; ++ks) {
      int byte = rloc * 256 + (ks * 32 + (lane >> 4) * 8) * 2;
      a[ks] = *(const short8*)(mb + (byte ^ ((rloc & 7) << 4)));
    }
#pragma unroll
    for (int ct = 0; ct < 5; ++ct) {
      f32x4 acc = {0.f, 0.f, 0.f, 0.f};
#pragma unroll
      for (int ks = 0; ks < 4; ++ks)
        acc = __builtin_amdgcn_mfma_f32_16x16x32_bf16(a[ks], bfg[ct][ks], acc, 0, 0, 0);
      float s = (acc[0] + acc[1]) + (acc[2] + acc[3]);
      float q = (acc[0] * acc[0] + acc[1] * acc[1]) +
                (acc[2] * acc[2] + acc[3] * acc[3]);
      s += __shfl_xor(s, 16);
      s += __shfl_xor(s, 32);
      q += __shfl_xor(q, 16);
      q += __shfl_xor(q, 32);
      int col = ct * 16 + (lane & 15);
      if ((lane >> 4) == 0 && col < 72) {
        atomicAdd(&ps[col], s);
        atomicAdd(&ps[80 + col], q);
      }
      int growb = r0 + w * 32 + rt * 16 + ((lane >> 4) << 2);
      if (col < 72) {
#pragma unroll
        for (int r = 0; r < 4; ++r) {
          int grow = growb + r;
          if (grow < N_HEDGES) z[(size_t)grow * 72 + col] = acc[r];
        }
      }
    }
  }
  __syncthreads();
  if (tid < 160) atomicAdd(&stats[tid], ps[tid]);
}

// ---- elementwise BN + sigmoid*softplus over Z -> ha (bf16) ----
__global__ __launch_bounds__(256) void k_hedge_apply(
    const float* __restrict__ z, const float* __restrict__ stats,
    const float* __restrict__ gf, const float* __restrict__ bf_,
    const float* __restrict__ gc, const float* __restrict__ bc_,
    unsigned short* __restrict__ hab) {
  int t = blockIdx.x * 256 + threadIdx.x;
  if (t >= N_HEDGES * 35) return;
  int r = t / 35, c = t - r * 35;
  const float inv = 1.f / N_HEDGES;
  float mf = stats[c] * inv;
  float vf = stats[80 + c] * inv - mf * mf;
  float mc = stats[36 + c] * inv;
  float vc = stats[116 + c] * inv - mc * mc;
  const float* zr = &z[(size_t)r * 72];
  float nf = (zr[c] - mf) * rsqrtf(vf + EPSB) * gf[c] + bf_[c];
  float nc = (zr[36 + c] - mc) * rsqrtf(vc + EPSB) * gc[c] + bc_[c];
  hab[t] = (unsigned short)bfr(sig_f(nf) * sp_f(nc));
}

// ---- per-node projection: U = x @ W[0:64,:], bf16 in, packed bf16x2 out ----
__global__ __launch_bounds__(256) void k_uv_node(const unsigned short* __restrict__ xb,
                                                 const float* __restrict__ f2w,
                                                 const float* __restrict__ c2w,
                                                 unsigned* __restrict__ Ufc) {
  __shared__ float wf[64 * 64];
  __shared__ float wc[64 * 64];
  __shared__ float rs[16][65];
  int tid = threadIdx.x;
  for (int i = tid; i < 64 * 64; i += 256) {
    wf[i] = f2w[i];
    wc[i] = c2w[i];
  }
  int r0 = blockIdx.x * 16;
  for (int i = tid; i < 16 * 64; i += 256) {
    int r = i >> 6, k = i & 63;
    rs[r][k] = bf2f(xb[(size_t)(r0 + r) * 64 + k]);
  }
  __syncthreads();
  int h = tid & 63, rb = tid >> 6;
  float af0 = 0, af1 = 0, af2 = 0, af3 = 0, ac0 = 0, ac1 = 0, ac2 = 0, ac3 = 0;
  for (int k = 0; k < 64; ++k) {
    float wfv = wf[k * 64 + h], wcv = wc[k * 64 + h];
    float m0 = rs[rb][k], m1 = rs[rb + 4][k], m2 = rs[rb + 8][k], m3 = rs[rb + 12][k];
    af0 += m0 * wfv; ac0 += m0 * wcv;
    af1 += m1 * wfv; ac1 += m1 * wcv;
    af2 += m2 * wfv; ac2 += m2 * wcv;
    af3 += m3 * wfv; ac3 += m3 * wcv;
  }
  int row = r0 + rb;
  Ufc[row * 64 + h] = pk2(af0, ac0);
  Ufc[(row + 4) * 64 + h] = pk2(af1, ac1);
  Ufc[(row + 8) * 64 + h] = pk2(af2, ac2);
  Ufc[(row + 12) * 64 + h] = pk2(af3, ac3);
}

// ---- per-hedge projection: V = ha @ W[64:99,:] + bias, bf16 in, packed bf16 out ----
__global__ __launch_bounds__(256) void k_uv_hedge(
    const unsigned short* __restrict__ hab, const float* __restrict__ f2wb,
    const float* __restrict__ c2wb, const float* __restrict__ f2b,
    const float* __restrict__ c2b, unsigned* __restrict__ Vfc) {
  __shared__ float wf[35 * 64];
  __shared__ float wc[35 * 64];
  __shared__ float rs[16][36];
  int tid = threadIdx.x;
  for (int i = tid; i < 35 * 64; i += 256) {
    wf[i] = f2wb[i];
    wc[i] = c2wb[i];
  }
  int r0 = blockIdx.x * 16;
  for (int i = tid; i < 16 * 35; i += 256) {
    int r = i / 35, k = i - r * 35;
    rs[r][k] = bf2f(hab[(r0 + r) * 35 + k]);
  }
  __syncthreads();
  int h = tid & 63, rb = tid >> 6;
  float af0, af1, af2, af3, ac0, ac1, ac2, ac3;
  af0 = af1 = af2 = af3 = f2b[h];
  ac0 = ac1 = ac2 = ac3 = c2b[h];
  for (int k = 0; k < 35; ++k) {
    float wfv = wf[k * 64 + h], wcv = wc[k * 64 + h];
    float m0 = rs[rb][k], m1 = rs[rb + 4][k], m2 = rs[rb + 8][k], m3 = rs[rb + 12][k];
    af0 += m0 * wfv; ac0 += m0 * wcv;
    af1 += m1 * wfv; ac1 += m1 * wcv;
    af2 += m2 * wfv; ac2 += m2 * wcv;
    af3 += m3 * wfv; ac3 += m3 * wcv;
  }
  int row = r0 + rb;
  Vfc[row * 64 + h] = pk2(af0, ac0);
  Vfc[(row + 4) * 64 + h] = pk2(af1, ac1);
  Vfc[(row + 8) * 64 + h] = pk2(af2, ac2);
  Vfc[(row + 12) * 64 + h] = pk2(af3, ac3);
}

// ------ per-node aggregate via CSR: packed bf16 U/V, unrolled x4, fast act ------
__device__ __forceinline__ float act2(float uf, float uc, unsigned v) {
  float a = uf + blo(v);
  float b = uc + bhi(v);
  return sig_f(a) * sp_f(b);
}
__global__ __launch_bounds__(256) void k_node_aggr(const int* __restrict__ permNh,
                                                   const int* __restrict__ offN,
                                                   const int* __restrict__ degN,
                                                   const unsigned* __restrict__ Ufc,
                                                   const unsigned* __restrict__ Vfc,
                                                   float* __restrict__ o) {
  int gt = blockIdx.x * 256 + threadIdx.x;
  int wid = gt >> 6, h = gt & 63;
  if (wid >= N_NODES) return;
  int off = offN[wid], d = degN[wid];
  unsigned u = Ufc[wid * 64 + h];
  float uf = blo(u), uc = bhi(u);
  float acc = 0.f;
  int k = 0;
  for (; k + 4 <= d; k += 4) {
    int h0 = permNh[off + k], h1 = permNh[off + k + 1];
    int h2 = permNh[off + k + 2], h3 = permNh[off + k + 3];
    unsigned v0 = Vfc[h0 * 64 + h];
    unsigned v1 = Vfc[h1 * 64 + h];
    unsigned v2 = Vfc[h2 * 64 + h];
    unsigned v3 = Vfc[h3 * 64 + h];
    acc += (act2(uf, uc, v0) + act2(uf, uc, v1)) +
           (act2(uf, uc, v2) + act2(uf, uc, v3));
  }
  for (; k < d; ++k) acc += act2(uf, uc, Vfc[permNh[off + k] * 64 + h]);
  o[wid * 64 + h] = acc / (float)max(d, 1);
}

// -------------------- BN stats over node features --------------------
__global__ __launch_bounds__(256) void k_ostats(const float* __restrict__ o,
                                                float* __restrict__ stats) {
  int h = threadIdx.x & 63;
  int rs = threadIdx.x >> 6;
  float s = 0.f, sq = 0.f;
  for (int r = blockIdx.x * 4 + rs; r < N_NODES; r += gridDim.x * 4) {
    float v = o[r * 64 + h];
    s += v;
    sq += v * v;
  }
  __shared__ float ls[4][2][64];
  ls[rs][0][h] = s;
  ls[rs][1][h] = sq;
  __syncthreads();
  if (threadIdx.x < 64) {
    float ts = ls[0][0][h] + ls[1][0][h] + ls[2][0][h] + ls[3][0][h];
    float tq = ls[0][1][h] + ls[1][1][h] + ls[2][1][h] + ls[3][1][h];
    atomicAdd(&stats[h], ts);
    atomicAdd(&stats[64 + h], tq);
  }
}

// ---------- x = softplus(BN(o_mean) + x), bf16 x in/out ----------
__global__ __launch_bounds__(256) void k_update(unsigned short* __restrict__ xb,
                                                const float* __restrict__ o,
                                                const float* __restrict__ stats,
                                                const float* __restrict__ g,
                                                const float* __restrict__ b) {
  int t = blockIdx.x * 256 + threadIdx.x;
  int h = t & 63;
  float mean = stats[h] * (1.f / N_NODES);
  float var = stats[64 + h] * (1.f / N_NODES) - mean * mean;
  float is = rsqrtf(var + EPSB);
  float v = (o[t] - mean) * is * g[h] + b[h];
  float r = sp_f(v + bf2f(xb[t]));
  xb[t] = (unsigned short)bfr(r);
}

// ------- graph pooling: chunked register accumulation (batch is sorted) -------
#define PR 512
__global__ __launch_bounds__(256) void k_pool(const unsigned short* __restrict__ xb,
                                              const int* __restrict__ batch,
                                              float* __restrict__ pooled,
                                              float* __restrict__ gcnt) {
  int h = threadIdx.x & 63, rs = threadIdx.x >> 6;
  int r0 = blockIdx.x * PR;
  int rend = min(r0 + PR, N_NODES);
  int gcur = -1;
  float acc = 0.f;
  int cnt = 0;
  for (int r = r0 + rs; r < rend; r += 4) {
    int g = batch[r];
    if (g != gcur) {
      if (gcur >= 0) {
        atomicAdd(&pooled[gcur * 64 + h], acc);
        if (h == 0) atomicAdd(&gcnt[gcur], (float)cnt);
      }
      gcur = g;
      acc = 0.f;
      cnt = 0;
    }
    acc += bf2f(xb[(size_t)r * 64 + h]);
    cnt++;
  }
  if (gcur >= 0) {
    atomicAdd(&pooled[gcur * 64 + h], acc);
    if (h == 0) atomicAdd(&gcnt[gcur], (float)cnt);
  }
}

// -------------------- final dense layers --------------------
__global__ __launch_bounds__(128) void k_final(const float* __restrict__ pooled,
                                               const float* __restrict__ gcnt,
                                               const float* __restrict__ l2w,
                                               const float* __restrict__ l2b,
                                               const float* __restrict__ ow,
                                               const float* __restrict__ ob,
                                               float* __restrict__ out) {
  int g = blockIdx.x;
  int t = threadIdx.x;
  __shared__ float row[64];
  __shared__ float hh[128];
  if (t < 64) row[t] = pooled[g * 64 + t] / fmaxf(gcnt[g], 1.f);
  __syncthreads();
  float acc = l2b[t];
  for (int k = 0; k < 64; ++k) acc += row[k] * l2w[k * 128 + t];
  hh[t] = sp_f(acc) * ow[t];
  __syncthreads();
  for (int s = 64; s > 0; s >>= 1) {
    if (t < s) hh[t] += hh[t + s];
    __syncthreads();
  }
  if (t == 0) out[g] = hh[0] + ob[0];
}

extern "C" void kernel_launch(void* const* d_in, const int* in_sizes, int n_in,
                              void* d_out, int out_size, void* d_ws, size_t ws_size,
                              hipStream_t stream) {
  const float* x_in = (const float*)d_in[0];
  const int* node_idx = (const int*)d_in[1];
  const int* hedge_idx = (const int*)d_in[2];
  const float* hedge_attr = (const float*)d_in[3];
  const int* batch = (const int*)d_in[4];
  const float* embed_w = (const float*)d_in[5];
  const float* embed_b = (const float*)d_in[6];
  const float* f1_w = (const float*)d_in[7];
  const float* c1_w = (const float*)d_in[9];
  const float* f2_w = (const float*)d_in[11];
  const float* f2_b = (const float*)d_in[12];
  const float* c2_w = (const float*)d_in[13];
  const float* c2_b = (const float*)d_in[14];
  const float* bnf_g = (const float*)d_in[15];
  const float* bnf_b = (const float*)d_in[16];
  const float* bnc_g = (const float*)d_in[17];
  const float* bnc_b = (const float*)d_in[18];
  const float* bno_g = (const float*)d_in[19];
  const float* bno_b = (const float*)d_in[20];
  const float* l2_w = (const float*)d_in[21];
  const float* l2_b = (const float*)d_in[22];
  const float* out_w = (const float*)d_in[23];
  const float* out_b = (const float*)d_in[24];

  // workspace layout (bytes, 256-aligned)
  char* base = (char*)d_ws;
  size_t off = 0;
  auto alloc = [&](size_t bytes) {
    size_t o = off;
    off = (off + bytes + 255) & ~(size_t)255;
    return o;
  };
  unsigned short* xbf = (unsigned short*)(base + alloc((size_t)N_NODES * 64 * 2));
  unsigned short* hab = (unsigned short*)(base + alloc((size_t)N_HEDGES * 35 * 2));
  // region R: Vfc (51.2MB) + obuf (25.6MB); zbuf (57.6MB) aliases R —
  // zbuf live gemm->apply only; Vfc (uv_hedge) and obuf (node_aggr) written after.
  unsigned* Vfc = (unsigned*)(base + alloc((size_t)N_HEDGES * 64 * 4));
  float* obuf = (float*)(base + alloc((size_t)N_NODES * 64 * 4));
  float* zbuf = (float*)Vfc;
  unsigned* Ufc = (unsigned*)(base + alloc((size_t)N_NODES * 64 * 4));
  uint4* wpk = (uint4*)(base + alloc((size_t)60 * 64 * 16));
  float* hstatsA = (float*)(base + alloc(3 * 160 * 4));  // adjacent: one memset
  float* ostatsA = (float*)(base + alloc(3 * 128 * 4));
  float* pooled = (float*)(base + alloc((size_t)N_GRAPHS * 64 * 4));  // adjacent: one memset
  float* gcnt = (float*)(base + alloc((size_t)N_GRAPHS * 4));
  int* degH = (int*)(base + alloc((size_t)N_HEDGES * 4));  // degH|degN|gctr adjacent
  int* degN = (int*)(base + alloc((size_t)N_NODES * 4));
  int* gctr = (int*)(base + alloc(2 * 4));
  int* offH = (int*)(base + alloc((size_t)N_HEDGES * 4));
  int* offN = (int*)(base + alloc((size_t)N_NODES * 4));
  int* rankH = (int*)(base + alloc((size_t)N_INC * 4));
  int* rankN = (int*)(base + alloc((size_t)N_INC * 4));
  int* permHn = (int*)(base + alloc((size_t)N_INC * 4));
  int* permNh = (int*)(base + alloc((size_t)N_INC * 4));
  (void)ws_size;
  (void)in_sizes;
  (void)n_in;
  (void)out_size;

  // ---- CSR build (ranks from hist; fill is atomic-free) ----
  hipMemsetAsync(degH, 0, (size_t)((char*)gctr - (char*)degH) + 2 * 4, stream);
  k_hist<<<(N_INC + 255) / 256, 256, 0, stream>>>(node_idx, hedge_idx, degN, degH,
                                                  rankN, rankH);
  k_alloc2<<<CHB + CNB, 256, 0, stream>>>(degH, degN, offH, offN, gctr);
  k_fill<<<(N_INC + 255) / 256, 256, 0, stream>>>(node_idx, hedge_idx, rankH, rankN,
                                                  offH, offN, permHn, permNh);
  k_wpack<<<60, 64, 0, stream>>>(f1_w, c1_w, wpk);
  k_cvt_ha<<<(N_HEDGES * 35 + 255) / 256, 256, 0, stream>>>(hedge_attr, hab,
                                                            N_HEDGES * 35);
  k_embed<<<N_NODES / 16, 256, 0, stream>>>(x_in, embed_w, embed_b, xbf);

  // zero all per-layer stats in one go
  hipMemsetAsync(hstatsA, 0, (size_t)((char*)ostatsA - (char*)hstatsA) + 3 * 128 * 4,
                 stream);

  for (int i = 0; i < 3; ++i) {
    float* hstats = hstatsA + i * 160;
    float* ostats = ostatsA + i * 128;

    // fused gather-mean + MFMA GEMM + stats
    k_hedge_gemm<<<(N_HEDGES + GR - 1) / GR, 256, 0, stream>>>(
        xbf, permHn, offH, degH, hab, wpk + (size_t)i * 20 * 64, zbuf, hstats);
    k_hedge_apply<<<(N_HEDGES * 35 + 255) / 256, 256, 0, stream>>>(
        zbuf, hstats, bnf_g + i * HE, bnf_b + i * HE, bnc_g + i * HE, bnc_b + i * HE,
        hab);

    // node/hedge projections (linearity split), packed bf16x2 outputs
    k_uv_node<<<N_NODES / 16, 256, 0, stream>>>(xbf, f2_w + i * CAT * 64,
                                                c2_w + i * CAT * 64, Ufc);
    k_uv_hedge<<<N_HEDGES / 16, 256, 0, stream>>>(
        hab, f2_w + i * CAT * 64 + 64 * 64, c2_w + i * CAT * 64 + 64 * 64,
        f2_b + i * 64, c2_b + i * 64, Vfc);

    // per-node combine via CSR (no atomics, mean folded in)
    k_node_aggr<<<N_NODES * 64 / 256, 256, 0, stream>>>(permNh, offN, degN, Ufc, Vfc,
                                                        obuf);

    // node BN + residual softplus
    k_ostats<<<1024, 256, 0, stream>>>(obuf, ostats);
    k_update<<<N_NODES * 64 / 256, 256, 0, stream>>>(xbf, obuf, ostats,
                                                     bno_g + i * 64, bno_b + i * 64);
  }

  // pooling + head
  hipMemsetAsync(pooled, 0, (size_t)((char*)gcnt - (char*)pooled) + N_GRAPHS * 4,
                 stream);
  k_pool<<<(N_NODES + PR - 1) / PR, 256, 0, stream>>>(xbf, batch, pooled, gcnt);
  k_final<<<N_GRAPHS, 128, 0, stream>>>(pooled, gcnt, l2_w, l2_b, out_w, out_b,
                                        (float*)d_out);
}